// Round 1
// baseline (635.600 us; speedup 1.0000x reference)
//
#include <hip/hip_runtime.h>
#include <cmath>

#define NN 10000
#define NE 160000
#define INV_SQRT_C 0.08838834764831845f   // 1/sqrt(128)
#define INV_SQRT3F 0.5773502691896258f

typedef _Float16 f16x8 __attribute__((ext_vector_type(8)));
typedef _Float16 f16x4 __attribute__((ext_vector_type(4)));
typedef _Float16 f16x2 __attribute__((ext_vector_type(2)));
typedef float    f32x4 __attribute__((ext_vector_type(4)));

__device__ __forceinline__ float silu_f(float x) {
  return x / (1.f + __expf(-x));
}

// ---------------------------------------------------------------------------
// Weight conversion fp32 -> fp16, B-fragment swizzle + column permutation
// (storage slot ct*16+m within a P-chunk holds logical col m*(P/16)+ct).
// ---------------------------------------------------------------------------
__global__ void wconv(const float* __restrict__ src, _Float16* __restrict__ dst,
                      int Korig, int Kpad, int N, float scale, int P) {
  int total = Kpad * N;
  for (int t = blockIdx.x * blockDim.x + threadIdx.x; t < total;
       t += gridDim.x * blockDim.x) {
    int n = t % N;
    int k = t / N;
    int kb = k >> 5, kk = k & 31;
    int sub = n & (P - 1);
    int n_l = (n & ~(P - 1)) | ((sub & 15) * (P >> 4) + (sub >> 4));
    float v = (k < Korig) ? src[(size_t)k * N + n_l] * scale : 0.f;
    dst[((size_t)(kb * N + n) << 5) + kk] = (_Float16)v;
  }
}

// ---------------------------------------------------------------------------
// Node pre-pass, fused: pass 0 (s-tile): up_s, sc_s, down. pass 1 (v-tile):
// up_v, sc_v. Same arithmetic as the verified 5-pass version.
// ---------------------------------------------------------------------------
__global__ __launch_bounds__(256) void node_pre_s(
    const float* __restrict__ feats,
    const float* __restrict__ W_up0, const float* __restrict__ W_skip0,
    const float* __restrict__ W_down,
    _Float16* __restrict__ UPH, _Float16* __restrict__ DOWNH,
    float* __restrict__ out_sc) {
  __shared__ float ls[16 * 128];
  const int n0 = blockIdx.x * 16;
  const int t = threadIdx.x;
  for (int f = t; f < 16 * 128; f += 256) {
    int r = f >> 7, c = f & 127;
    ls[r * 128 + c] = feats[(size_t)(n0 + r) * 512 + c];
  }
  __syncthreads();
  {
    int j = t & 127, g = t >> 7;  // 8 nodes per group
    float au[8] = {0, 0, 0, 0, 0, 0, 0, 0};
    float ak[8] = {0, 0, 0, 0, 0, 0, 0, 0};
    for (int i = 0; i < 128; ++i) {
      float wu = W_up0[(size_t)i * 128 + j];
      float wk = W_skip0[(size_t)i * 128 + j];
#pragma unroll
      for (int r = 0; r < 8; ++r) {
        float s = ls[(g * 8 + r) * 128 + i];
        au[r] += s * wu;
        ak[r] += s * wk;
      }
    }
#pragma unroll
    for (int r = 0; r < 8; ++r) {
      int n = n0 + g * 8 + r;
      UPH[(size_t)n * 512 + j] = (_Float16)(au[r] * INV_SQRT_C);
      out_sc[(size_t)n * 512 + j] = ak[r] * INV_SQRT_C;
    }
  }
  {
    int j = t & 63, g = t >> 6;  // 4 nodes per group
    float ad[4] = {0, 0, 0, 0};
    for (int i = 0; i < 128; ++i) {
      float wd = W_down[(size_t)i * 64 + j];
#pragma unroll
      for (int r = 0; r < 4; ++r) ad[r] += ls[(g * 4 + r) * 128 + i] * wd;
    }
#pragma unroll
    for (int r = 0; r < 4; ++r)
      DOWNH[(size_t)(n0 + g * 4 + r) * 64 + j] = (_Float16)(ad[r] * INV_SQRT_C);
  }
}

__global__ __launch_bounds__(256) void node_pre_v(
    const float* __restrict__ feats,
    const float* __restrict__ W_up1, const float* __restrict__ W_skip1,
    _Float16* __restrict__ UPH, float* __restrict__ out_sc) {
  __shared__ float ls[16 * 384];
  const int n0 = blockIdx.x * 16;
  const int t = threadIdx.x;
  for (int f = t; f < 16 * 384; f += 256) {
    int r = f / 384, c = f % 384;
    ls[r * 384 + c] = feats[(size_t)(n0 + r) * 512 + 128 + c];
  }
  __syncthreads();
  int j = t & 127, g = t >> 7;
  float au[8][3], ak[8][3];
#pragma unroll
  for (int r = 0; r < 8; ++r)
#pragma unroll
    for (int c = 0; c < 3; ++c) { au[r][c] = 0.f; ak[r][c] = 0.f; }
  for (int i = 0; i < 128; ++i) {
    float wu = W_up1[(size_t)i * 128 + j];
    float wk = W_skip1[(size_t)i * 128 + j];
#pragma unroll
    for (int r = 0; r < 8; ++r) {
#pragma unroll
      for (int c = 0; c < 3; ++c) {
        float v = ls[(g * 8 + r) * 384 + i * 3 + c];
        au[r][c] += v * wu;
        ak[r][c] += v * wk;
      }
    }
  }
#pragma unroll
  for (int r = 0; r < 8; ++r) {
    int n = n0 + g * 8 + r;
#pragma unroll
    for (int c = 0; c < 3; ++c) {
      UPH[(size_t)n * 512 + 128 + j * 3 + c] = (_Float16)(au[r][c] * INV_SQRT_C);
      out_sc[(size_t)n * 512 + 128 + j * 3 + c] = ak[r][c] * INV_SQRT_C;
    }
  }
}

// ---------------------------------------------------------------------------
// CSR build (parameterized by edge_index column: 0=sender, 1=receiver).
// ---------------------------------------------------------------------------
__global__ void k_count(const int* __restrict__ edge_index, int* __restrict__ CNT,
                        int col) {
  int e = blockIdx.x * blockDim.x + threadIdx.x;
  if (e < NE) atomicAdd(&CNT[edge_index[e * 2 + col]], 1);
}

__global__ __launch_bounds__(1024) void k_scan(const int* __restrict__ CNT,
                                               int* __restrict__ OFF,
                                               int* __restrict__ CUR) {
  __shared__ int ts[1024];
  const int t = threadIdx.x;
  const int base = t * 10;
  int loc[10];
  int s = 0;
#pragma unroll
  for (int i = 0; i < 10; ++i) {
    int idx = base + i;
    int v = (idx < NN) ? CNT[idx] : 0;
    loc[i] = s;
    s += v;
  }
  ts[t] = s;
  __syncthreads();
  for (int off = 1; off < 1024; off <<= 1) {
    int v = (t >= off) ? ts[t - off] : 0;
    __syncthreads();
    ts[t] += v;
    __syncthreads();
  }
  int tp = (t > 0) ? ts[t - 1] : 0;
#pragma unroll
  for (int i = 0; i < 10; ++i) {
    int idx = base + i;
    if (idx < NN) {
      OFF[idx] = tp + loc[i];
      CUR[idx] = tp + loc[i];
    }
  }
  if (t == 1023) OFF[NN] = ts[1023];
}

__global__ void k_fill(const int* __restrict__ edge_index, int* __restrict__ CUR,
                       int* __restrict__ IDX, int col) {
  int e = blockIdx.x * blockDim.x + threadIdx.x;
  if (e < NE) {
    int r = edge_index[e * 2 + col];
    int pos = atomicAdd(&CUR[r], 1);
    IDX[pos] = e;
  }
}

// ---------------------------------------------------------------------------
// In-place MLP layer: full layer accumulated in registers, barrier once all
// reads of Buf are done, then overwrite Buf. Saves the 32 KB ping-pong buffer
// (LDS 64->48 KB => 3 blocks/CU instead of 2). Caller barriers after.
// ---------------------------------------------------------------------------
__device__ __forceinline__ void mlp_layer_ip(
    _Float16* Buf, const _Float16* __restrict__ Wz,
    int m, int g, int wv) {
  f32x4 acc[4][4];
  f32x4 zero4 = {0.f, 0.f, 0.f, 0.f};
#pragma unroll
  for (int rt = 0; rt < 4; ++rt)
#pragma unroll
    for (int ct = 0; ct < 4; ++ct) acc[rt][ct] = zero4;

#pragma unroll
  for (int kb = 0; kb < 8; ++kb) {
    f16x8 a[4], b[4];
#pragma unroll
    for (int rt = 0; rt < 4; ++rt) {
      int row = rt * 16 + m;
      a[rt] = *(const f16x8*)&Buf[row * 256 + (((kb * 2 + (g >> 1)) ^ m) << 4) + (g & 1) * 8];
    }
#pragma unroll
    for (int ct = 0; ct < 4; ++ct)
      b[ct] = *(const f16x8*)&Wz[((size_t)(kb * 256 + wv * 64 + ct * 16 + m) << 5) + g * 8];
#pragma unroll
    for (int rt = 0; rt < 4; ++rt)
#pragma unroll
      for (int ct = 0; ct < 4; ++ct)
        acc[rt][ct] = __builtin_amdgcn_mfma_f32_16x16x32_f16(a[rt], b[ct], acc[rt][ct], 0, 0, 0);
  }
  __syncthreads();  // all reads of Buf complete before in-place overwrite
#pragma unroll
  for (int rt = 0; rt < 4; ++rt)
#pragma unroll
    for (int q = 0; q < 4; ++q) {
      int row = rt * 16 + g * 4 + q;
      f16x4 pk;
#pragma unroll
      for (int ct = 0; ct < 4; ++ct) pk[ct] = (_Float16)silu_f(acc[rt][ct][q]);
      int blk = (wv * 4 + (m >> 2)) ^ (row & 15);
      *(f16x4*)&Buf[row * 256 + (blk << 4) + (m & 3) * 4] = pk;
    }
}

// ---------------------------------------------------------------------------
// Fused edge kernel — 64 edges/block, 256 threads (4 waves), sender-sorted
// order (SIDX). LDS cut to 48 KB (+1.25 KB staging) for 3 blocks/CU:
//   - MLP layers run in place on HA (register-accumulate, barrier, overwrite)
//   - epilogue SW and SP merged into one 16 KB buffer SWP. Every tp_* reads
//     exactly the per-thread offsets it writes (in-place safe, same-wave DS
//     ordering — same assumption as the verified sw_write->tp_xs pattern),
//     so barrier count matches the previous schedule.
//   - SIDX + edge_attrs for the block staged once in LDS (kills the repeated
//     scattered global loads in the MIDs write sections).
// ---------------------------------------------------------------------------
__global__ __launch_bounds__(256, 3) void edge_mlp(
    const float* __restrict__ edge_attrs,
    const float* __restrict__ edge_feats,
    const int* __restrict__ edge_index,
    const int* __restrict__ SIDX,
    const _Float16* __restrict__ DOWNH,
    const _Float16* __restrict__ UPH,
    const _Float16* __restrict__ W0h, const _Float16* __restrict__ W1h,
    const _Float16* __restrict__ W2h, const _Float16* __restrict__ W3h,
    const _Float16* __restrict__ WL0h, const _Float16* __restrict__ WL1h,
    _Float16* __restrict__ MIDs) {
  __shared__ _Float16 HA[64 * 256];    // 32 KB — MLP in-place + h3
  __shared__ _Float16 SWP[64 * 128];   // 16 KB — merged SW/SP scratch
  __shared__ int    SIDs[64];
  __shared__ float4 EAs[64];

  const int tid = threadIdx.x;
  const int lane = tid & 63;
  const int wv = tid >> 6;
  const int m = lane & 15;
  const int g = lane >> 4;
  const int e0 = blockIdx.x * 64;
  const int nw = wv * 64;

  // stage block edge ids + attrs (visible after the layer-0 barrier)
  if (tid < 64) {
    int el = SIDX[e0 + tid];
    SIDs[tid] = el;
    EAs[tid] = *(const float4*)&edge_attrs[(size_t)el * 4];
  }

  int el_r[4], snd_r[4], rcv_r[4];
#pragma unroll
  for (int rt = 0; rt < 4; ++rt) {
    el_r[rt] = SIDX[e0 + rt * 16 + m];
    int2 sr = *(const int2*)&edge_index[(size_t)el_r[rt] * 2];
    snd_r[rt] = sr.x;
    rcv_r[rt] = sr.y;
  }

  f32x4 zero4 = {0.f, 0.f, 0.f, 0.f};
  f16x8 zf = {0, 0, 0, 0, 0, 0, 0, 0};

  // ---------------- layer 0: aug(136, padded 160) -> h1 (HA)
  {
    f32x4 acc[4][4];
#pragma unroll
    for (int rt = 0; rt < 4; ++rt)
#pragma unroll
      for (int ct = 0; ct < 4; ++ct) acc[rt][ct] = zero4;

#pragma unroll
    for (int kb = 0; kb < 5; ++kb) {
      const int k0 = kb * 32 + g * 8;
      f16x8 a[4], b[4];
#pragma unroll
      for (int rt = 0; rt < 4; ++rt) {
        if (k0 == 0) {
          const float* ef = &edge_feats[(size_t)el_r[rt] * 8];
          float4 f0 = *(const float4*)ef;
          float4 f1 = *(const float4*)(ef + 4);
          f16x8 av;
          av[0] = (_Float16)f0.x; av[1] = (_Float16)f0.y;
          av[2] = (_Float16)f0.z; av[3] = (_Float16)f0.w;
          av[4] = (_Float16)f1.x; av[5] = (_Float16)f1.y;
          av[6] = (_Float16)f1.z; av[7] = (_Float16)f1.w;
          a[rt] = av;
        } else if (k0 < 72) {
          a[rt] = *(const f16x8*)&DOWNH[(size_t)snd_r[rt] * 64 + (k0 - 8)];
        } else if (k0 < 136) {
          a[rt] = *(const f16x8*)&DOWNH[(size_t)rcv_r[rt] * 64 + (k0 - 72)];
        } else {
          a[rt] = zf;
        }
      }
#pragma unroll
      for (int ct = 0; ct < 4; ++ct)
        b[ct] = *(const f16x8*)&W0h[((size_t)(kb * 256 + nw + ct * 16 + m) << 5) + g * 8];
#pragma unroll
      for (int rt = 0; rt < 4; ++rt)
#pragma unroll
        for (int ct = 0; ct < 4; ++ct)
          acc[rt][ct] = __builtin_amdgcn_mfma_f32_16x16x32_f16(a[rt], b[ct], acc[rt][ct], 0, 0, 0);
    }
#pragma unroll
    for (int rt = 0; rt < 4; ++rt)
#pragma unroll
      for (int q = 0; q < 4; ++q) {
        int row = rt * 16 + g * 4 + q;
        f16x4 pk;
#pragma unroll
        for (int ct = 0; ct < 4; ++ct) pk[ct] = (_Float16)silu_f(acc[rt][ct][q]);
        int blk = (wv * 4 + (m >> 2)) ^ (row & 15);
        *(f16x4*)&HA[row * 256 + (blk << 4) + (m & 3) * 4] = pk;
      }
  }
  __syncthreads();

  mlp_layer_ip(HA, W1h, m, g, wv);   // layer 1: h1 -> h2 (in place)
  __syncthreads();
  mlp_layer_ip(HA, W2h, m, g, wv);   // layer 2: h2 -> h3 (in place)
  __syncthreads();
  // HA = h3, read-only from here on.

  // ================= epilogue =================
  const int e_loc = lane;
  const int ers = (e_loc ^ (e_loc >> 3)) & 7;
  const int elc = SIDs[e_loc];
  const int snd_e = edge_index[(size_t)elc * 2];
  const _Float16* uprow = &UPH[(size_t)snd_e * 512];

  // quarter GEMM into caller-provided acc buffer (reads HA only)
  auto qgemm = [&](int qbase, f32x4 (&accq)[4][2]) {
#pragma unroll
    for (int rt = 0; rt < 4; ++rt)
#pragma unroll
      for (int ct = 0; ct < 2; ++ct) accq[rt][ct] = zero4;
#pragma unroll
    for (int kb = 0; kb < 8; ++kb) {
      f16x8 a[4], b[2];
#pragma unroll
      for (int rt = 0; rt < 4; ++rt) {
        int row = rt * 16 + m;
        a[rt] = *(const f16x8*)&HA[row * 256 + (((kb * 2 + (g >> 1)) ^ m) << 4) + (g & 1) * 8];
      }
#pragma unroll
      for (int ct = 0; ct < 2; ++ct)
        b[ct] = *(const f16x8*)&W3h[((size_t)(kb * 512 + qbase + wv * 32 + ct * 16 + m) << 5) + g * 8];
#pragma unroll
      for (int rt = 0; rt < 4; ++rt)
#pragma unroll
        for (int ct = 0; ct < 2; ++ct)
          accq[rt][ct] = __builtin_amdgcn_mfma_f32_16x16x32_f16(a[rt], b[ct], accq[rt][ct], 0, 0, 0);
    }
  };

  auto sw_write = [&](const f32x4 (&accq)[4][2]) {
#pragma unroll
    for (int rt = 0; rt < 4; ++rt)
#pragma unroll
      for (int r4 = 0; r4 < 4; ++r4) {
        int row = rt * 16 + g * 4 + r4;
        int rs = (row ^ (row >> 3)) & 7;
        f16x2 pk;
        pk[0] = (_Float16)accq[rt][0][r4];
        pk[1] = (_Float16)accq[rt][1][r4];
        int blk = ((wv * 2 + (m >> 3)) ^ rs) & 7;
        *(f16x2*)&SWP[row * 128 + (blk << 4) + (m & 7) * 2] = pk;
      }
  };

  auto fold = [&](const _Float16* __restrict__ WLh, int qpart, f32x4 (&P)[4][2]) {
#pragma unroll
    for (int rt = 0; rt < 4; ++rt)
#pragma unroll
      for (int ct = 0; ct < 2; ++ct) P[rt][ct] = zero4;
#pragma unroll
    for (int kb = 0; kb < 4; ++kb) {
      f16x8 a[4], b[2];
#pragma unroll
      for (int rt = 0; rt < 4; ++rt) {
        int row = rt * 16 + m;
        int rs = (row ^ (row >> 3)) & 7;
        a[rt] = *(const f16x8*)&SWP[row * 128 + ((((kb * 2 + (g >> 1)) ^ rs) & 7) << 4) + (g & 1) * 8];
      }
#pragma unroll
      for (int ct = 0; ct < 2; ++ct)
        b[ct] = *(const f16x8*)&WLh[((size_t)((qpart * 4 + kb) * 128 + wv * 32 + ct * 16 + m) << 5) + g * 8];
#pragma unroll
      for (int rt = 0; rt < 4; ++rt)
#pragma unroll
        for (int ct = 0; ct < 2; ++ct)
          P[rt][ct] = __builtin_amdgcn_mfma_f32_16x16x32_f16(a[rt], b[ct], P[rt][ct], 0, 0, 0);
    }
  };

  // in-place: each thread reads ONLY the 4 f16x8 slots it writes back
  auto tp_xs = [&]() {
#pragma unroll
    for (int cch = 0; cch < 4; ++cch) {
      int ib = nw / 2 + cch * 8;
      int blk = ((ib >> 4) ^ ers) & 7;
      int off = e_loc * 128 + (blk << 4) + (ib & 15);
      f16x8 swv = *(const f16x8*)&SWP[off];
      f16x8 upv = *(const f16x8*)&uprow[ib];
      f16x8 pr = swv * upv;
      *(f16x8*)&SWP[off] = pr;
    }
  };

  _Float16 xvb[96];
  auto load_xv = [&]() {
#pragma unroll
    for (int u = 0; u < 12; ++u) {
      f16x8 t = *(const f16x8*)&uprow[128 + wv * 96 + u * 8];
#pragma unroll
      for (int z = 0; z < 8; ++z) xvb[u * 8 + z] = t[z];
    }
  };

  auto tp_w4 = [&]() {
    float4 ea = EAs[e_loc];
#pragma unroll
    for (int cch = 0; cch < 4; ++cch) {
      int ib = nw / 2 + cch * 8;
      int blk = ((ib >> 4) ^ ers) & 7;
      int off = e_loc * 128 + (blk << 4) + (ib & 15);
      f16x8 swv = *(const f16x8*)&SWP[off];
      f16x8 outv;
#pragma unroll
      for (int z = 0; z < 8; ++z) {
        int k = cch * 8 + z;
        float d = (float)xvb[k * 3] * ea.y + (float)xvb[k * 3 + 1] * ea.z +
                  (float)xvb[k * 3 + 2] * ea.w;
        outv[z] = (_Float16)((float)swv[z] * d);
      }
      *(f16x8*)&SWP[off] = outv;
    }
  };

  f32x4 accqA[4][2], accqB[4][2];
  f32x4 P1[4][2], P4[4][2], P2[4][2], P3[4][2];

  // ---- q1 (w1): SWP <- w1 -> A1 (in place) ; P1 = A1 @ WL0a
  qgemm(0, accqA);
  sw_write(accqA);            // SWP <- w1  (wave-owned column blocks)
  tp_xs();                    // SWP: w1 -> A1 (same-wave columns, in place)
  qgemm(384, accqB);          // w4, independent — fills the barrier wait
  __syncthreads();            // B1: A1 complete (all waves)
  fold(WL0h, 0, P1);          // cross-wave read of SWP(A1)
  load_xv();
  __syncthreads();            // B2: folds done reading A1
  sw_write(accqB);            // SWP <- w4
  tp_w4();                    // SWP: w4 -> A4 (same-wave, in place)
  qgemm(128, accqA);          // w2 queued
  __syncthreads();            // B3: A4 complete
  fold(WL0h, 1, P4);
  __syncthreads();            // B4: folds done reading A4
  sw_write(accqA);            // SWP <- w2
  tp_xs();                    // SWP: w2 -> A2 (same-wave, in place)
  qgemm(256, accqB);          // w3 queued

  // scalar part: MIDs[:, j] = y0*P1 + P4/sqrt(3)  (global only — overlaps)
#pragma unroll
  for (int rt = 0; rt < 4; ++rt)
#pragma unroll
    for (int r4 = 0; r4 < 4; ++r4) {
      int row = rt * 16 + g * 4 + r4;
      int elw = SIDs[row];
      float4 ea = EAs[row];
      f16x2 pk;
      pk[0] = (_Float16)(ea.x * P1[rt][0][r4] + INV_SQRT3F * P4[rt][0][r4]);
      pk[1] = (_Float16)(ea.x * P1[rt][1][r4] + INV_SQRT3F * P4[rt][1][r4]);
      *(f16x2*)&MIDs[(size_t)elw * 512 + wv * 32 + m * 2] = pk;
    }
  __syncthreads();            // B5: A2 complete
  fold(WL1h, 0, P2);
  __syncthreads();            // B6: folds done reading A2
  sw_write(accqB);            // SWP <- w3

  // hoist this thread's w3 slots to regs (read 3x below), then per-plane
  // in-place A3c writes at the exact offsets just read.
  f16x8 w3r[4];
#pragma unroll
  for (int cch = 0; cch < 4; ++cch) {
    int ib = nw / 2 + cch * 8;
    int blk = ((ib >> 4) ^ ers) & 7;
    w3r[cch] = *(const f16x8*)&SWP[e_loc * 128 + (blk << 4) + (ib & 15)];
  }

#pragma unroll
  for (int c = 0; c < 3; ++c) {
    // SWP <- A3c = w3 (.) xv_c
#pragma unroll
    for (int cch = 0; cch < 4; ++cch) {
      int ib = nw / 2 + cch * 8;
      int blk = ((ib >> 4) ^ ers) & 7;
      int off = e_loc * 128 + (blk << 4) + (ib & 15);
      f16x8 outv;
#pragma unroll
      for (int z = 0; z < 8; ++z)
        outv[z] = w3r[cch][z] * xvb[(cch * 8 + z) * 3 + c];
      *(f16x8*)&SWP[off] = outv;
    }
    __syncthreads();          // A3c complete
    fold(WL1h, 1, P3);
    // plane c: MIDs[:, 128 + c*128 + j] = yv[c]*P2 + y0*P3
#pragma unroll
    for (int rt = 0; rt < 4; ++rt)
#pragma unroll
      for (int r4 = 0; r4 < 4; ++r4) {
        int row = rt * 16 + g * 4 + r4;
        int elw = SIDs[row];
        float4 ea = EAs[row];
        float yvc = (c == 0) ? ea.y : (c == 1) ? ea.z : ea.w;
        f16x2 pk;
        pk[0] = (_Float16)(yvc * P2[rt][0][r4] + ea.x * P3[rt][0][r4]);
        pk[1] = (_Float16)(yvc * P2[rt][1][r4] + ea.x * P3[rt][1][r4]);
        *(f16x2*)&MIDs[(size_t)elw * 512 + 128 + c * 128 + wv * 32 + m * 2] = pk;
      }
    if (c < 2) __syncthreads();  // folds done reading A3c before next write
  }
}

// ---------------------------------------------------------------------------
// Gather: one block per node; LDS-staged edge ids + 4-way unroll; output row
// staged in LDS and stored coalesced (float2/lane) instead of 4-strided.
// ---------------------------------------------------------------------------
__global__ __launch_bounds__(256) void gather_msg(
    const _Float16* __restrict__ MIDs, const int* __restrict__ OFF,
    const int* __restrict__ EIDX, float* __restrict__ out) {
  __shared__ int eb[256];
  __shared__ float os[512];
  const int n = blockIdx.x;
  const int t = threadIdx.x;
  const int beg = OFF[n], end = OFF[n + 1];
  float a0 = 0.f, a1 = 0.f;
  for (int base = beg; base < end; base += 256) {
    int cnt = min(256, end - base);
    __syncthreads();
    if (t < cnt) eb[t] = EIDX[base + t];
    __syncthreads();
    int k = 0;
    for (; k + 4 <= cnt; k += 4) {
      int e0_ = eb[k], e1_ = eb[k + 1], e2_ = eb[k + 2], e3_ = eb[k + 3];
      f16x2 v0 = *(const f16x2*)&MIDs[(size_t)e0_ * 512 + t * 2];
      f16x2 v1 = *(const f16x2*)&MIDs[(size_t)e1_ * 512 + t * 2];
      f16x2 v2 = *(const f16x2*)&MIDs[(size_t)e2_ * 512 + t * 2];
      f16x2 v3 = *(const f16x2*)&MIDs[(size_t)e3_ * 512 + t * 2];
      a0 += (float)v0[0] + (float)v1[0] + (float)v2[0] + (float)v3[0];
      a1 += (float)v0[1] + (float)v1[1] + (float)v2[1] + (float)v3[1];
    }
    for (; k < cnt; ++k) {
      f16x2 v = *(const f16x2*)&MIDs[(size_t)eb[k] * 512 + t * 2];
      a0 += (float)v[0];
      a1 += (float)v[1];
    }
  }
#pragma unroll
  for (int u = 0; u < 2; ++u) {
    int x = t * 2 + u;
    float a = u ? a1 : a0;
    int dst;
    if (x < 128) {
      dst = x * 4;
    } else {
      int xm = x - 128;
      int c = xm >> 7, j = xm & 127;
      dst = j * 4 + 1 + c;
    }
    os[dst] = a;
  }
  __syncthreads();
  *(float2*)&out[(size_t)n * 512 + t * 2] = *(const float2*)&os[t * 2];
}

// ---------------------------------------------------------------------------
extern "C" void kernel_launch(void* const* d_in, const int* in_sizes, int n_in,
                              void* d_out, int out_size, void* d_ws, size_t ws_size,
                              hipStream_t stream) {
  const float* node_feats = (const float*)d_in[1];
  const float* edge_attrs = (const float*)d_in[2];
  const float* edge_feats = (const float*)d_in[3];
  const int*   edge_index = (const int*)d_in[4];
  const float* W_up0   = (const float*)d_in[5];
  const float* W_up1   = (const float*)d_in[6];
  const float* W_down  = (const float*)d_in[7];
  const float* Wm0     = (const float*)d_in[8];
  const float* Wm1     = (const float*)d_in[9];
  const float* Wm2     = (const float*)d_in[10];
  const float* Wm3     = (const float*)d_in[11];
  const float* W_lin0  = (const float*)d_in[12];
  const float* W_lin1  = (const float*)d_in[13];
  const float* W_skip0 = (const float*)d_in[14];
  const float* W_skip1 = (const float*)d_in[15];
  float* out = (float*)d_out;

  char* ws = (char*)d_ws;
  size_t off = 0;
  auto alloc = [&](size_t bytes) {
    void* p = ws + off;
    off = (off + bytes + 255) & ~(size_t)255;
    return p;
  };
  _Float16* UPH   = (_Float16*)alloc((size_t)NN * 512 * 2);
  _Float16* DOWNH = (_Float16*)alloc((size_t)NN * 64 * 2);
  _Float16* W0h   = (_Float16*)alloc(160 * 256 * 2);
  _Float16* W1h   = (_Float16*)alloc(256 * 256 * 2);
  _Float16* W2h   = (_Float16*)alloc(256 * 256 * 2);
  _Float16* W3h   = (_Float16*)alloc(256 * 512 * 2);
  _Float16* WL0h  = (_Float16*)alloc(256 * 128 * 2);
  _Float16* WL1h  = (_Float16*)alloc(256 * 128 * 2);
  int*      CNT   = (int*)alloc((size_t)NN * 4);
  int*      OFF   = (int*)alloc((size_t)(NN + 1) * 4);
  int*      CUR   = (int*)alloc((size_t)NN * 4);
  int*      EIDX  = (int*)alloc((size_t)NE * 4);
  int*      CNT2  = (int*)alloc((size_t)NN * 4);
  int*      OFF2  = (int*)alloc((size_t)(NN + 1) * 4);
  int*      CUR2  = (int*)alloc((size_t)NN * 4);
  int*      SIDX  = (int*)alloc((size_t)NE * 4);
  _Float16* MIDs  = (_Float16*)alloc((size_t)NE * 512 * 2);

  hipMemsetAsync(CNT, 0, (size_t)NN * 4, stream);
  hipMemsetAsync(CNT2, 0, (size_t)NN * 4, stream);

  // scales folded into fp16 weights: 1/sqrt(136) layer0, 1/16 layers 1..3,
  // 1/256 for W_lin (includes sqrt(2C) and AVG_NEIGH)
  wconv<<<160, 256, 0, stream>>>(Wm0, W0h, 136, 160, 256, 1.0f / sqrtf(136.0f), 64);
  wconv<<<256, 256, 0, stream>>>(Wm1, W1h, 256, 256, 256, 0.0625f, 64);
  wconv<<<256, 256, 0, stream>>>(Wm2, W2h, 256, 256, 256, 0.0625f, 64);
  wconv<<<512, 256, 0, stream>>>(Wm3, W3h, 256, 256, 512, 0.0625f, 32);
  wconv<<<128, 256, 0, stream>>>(W_lin0, WL0h, 256, 256, 128, 1.0f / 256.0f, 32);
  wconv<<<128, 256, 0, stream>>>(W_lin1, WL1h, 256, 256, 128, 1.0f / 256.0f, 32);

  node_pre_s<<<625, 256, 0, stream>>>(node_feats, W_up0, W_skip0, W_down,
                                      UPH, DOWNH, out + (size_t)NN * 512);
  node_pre_v<<<625, 256, 0, stream>>>(node_feats, W_up1, W_skip1,
                                      UPH, out + (size_t)NN * 512);

  // receiver CSR (gather) + sender CSR (edge processing order)
  k_count<<<625, 256, 0, stream>>>(edge_index, CNT, 1);
  k_count<<<625, 256, 0, stream>>>(edge_index, CNT2, 0);
  k_scan<<<1, 1024, 0, stream>>>(CNT, OFF, CUR);
  k_scan<<<1, 1024, 0, stream>>>(CNT2, OFF2, CUR2);
  k_fill<<<625, 256, 0, stream>>>(edge_index, CUR, EIDX, 1);
  k_fill<<<625, 256, 0, stream>>>(edge_index, CUR2, SIDX, 0);

  edge_mlp<<<2500, 256, 0, stream>>>(edge_attrs, edge_feats, edge_index, SIDX,
                                     DOWNH, UPH, W0h, W1h, W2h, W3h, WL0h, WL1h,
                                     MIDs);
  gather_msg<<<NN, 256, 0, stream>>>(MIDs, OFF, EIDX, out);
}

// Round 2
// 609.201 us; speedup vs baseline: 1.0433x; 1.0433x over previous
//
#include <hip/hip_runtime.h>
#include <cmath>

#define NN 10000
#define NE 160000
#define INV_SQRT_C 0.08838834764831845f   // 1/sqrt(128)
#define INV_SQRT3F 0.5773502691896258f

typedef _Float16 f16x8 __attribute__((ext_vector_type(8)));
typedef _Float16 f16x4 __attribute__((ext_vector_type(4)));
typedef _Float16 f16x2 __attribute__((ext_vector_type(2)));
typedef float    f32x4 __attribute__((ext_vector_type(4)));

__device__ __forceinline__ float silu_f(float x) {
  return x / (1.f + __expf(-x));
}

// ---------------------------------------------------------------------------
// Weight conversion fp32 -> fp16, B-fragment swizzle + column permutation
// (storage slot ct*16+m within a P-chunk holds logical col m*(P/16)+ct).
// ---------------------------------------------------------------------------
__global__ void wconv(const float* __restrict__ src, _Float16* __restrict__ dst,
                      int Korig, int Kpad, int N, float scale, int P) {
  int total = Kpad * N;
  for (int t = blockIdx.x * blockDim.x + threadIdx.x; t < total;
       t += gridDim.x * blockDim.x) {
    int n = t % N;
    int k = t / N;
    int kb = k >> 5, kk = k & 31;
    int sub = n & (P - 1);
    int n_l = (n & ~(P - 1)) | ((sub & 15) * (P >> 4) + (sub >> 4));
    float v = (k < Korig) ? src[(size_t)k * N + n_l] * scale : 0.f;
    dst[((size_t)(kb * N + n) << 5) + kk] = (_Float16)v;
  }
}

// ---------------------------------------------------------------------------
// Node pre-pass, fused: pass 0 (s-tile): up_s, sc_s, down. pass 1 (v-tile):
// up_v, sc_v. Same arithmetic as the verified 5-pass version.
// ---------------------------------------------------------------------------
__global__ __launch_bounds__(256) void node_pre_s(
    const float* __restrict__ feats,
    const float* __restrict__ W_up0, const float* __restrict__ W_skip0,
    const float* __restrict__ W_down,
    _Float16* __restrict__ UPH, _Float16* __restrict__ DOWNH,
    float* __restrict__ out_sc) {
  __shared__ float ls[16 * 128];
  const int n0 = blockIdx.x * 16;
  const int t = threadIdx.x;
  for (int f = t; f < 16 * 128; f += 256) {
    int r = f >> 7, c = f & 127;
    ls[r * 128 + c] = feats[(size_t)(n0 + r) * 512 + c];
  }
  __syncthreads();
  {
    int j = t & 127, g = t >> 7;  // 8 nodes per group
    float au[8] = {0, 0, 0, 0, 0, 0, 0, 0};
    float ak[8] = {0, 0, 0, 0, 0, 0, 0, 0};
    for (int i = 0; i < 128; ++i) {
      float wu = W_up0[(size_t)i * 128 + j];
      float wk = W_skip0[(size_t)i * 128 + j];
#pragma unroll
      for (int r = 0; r < 8; ++r) {
        float s = ls[(g * 8 + r) * 128 + i];
        au[r] += s * wu;
        ak[r] += s * wk;
      }
    }
#pragma unroll
    for (int r = 0; r < 8; ++r) {
      int n = n0 + g * 8 + r;
      UPH[(size_t)n * 512 + j] = (_Float16)(au[r] * INV_SQRT_C);
      out_sc[(size_t)n * 512 + j] = ak[r] * INV_SQRT_C;
    }
  }
  {
    int j = t & 63, g = t >> 6;  // 4 nodes per group
    float ad[4] = {0, 0, 0, 0};
    for (int i = 0; i < 128; ++i) {
      float wd = W_down[(size_t)i * 64 + j];
#pragma unroll
      for (int r = 0; r < 4; ++r) ad[r] += ls[(g * 4 + r) * 128 + i] * wd;
    }
#pragma unroll
    for (int r = 0; r < 4; ++r)
      DOWNH[(size_t)(n0 + g * 4 + r) * 64 + j] = (_Float16)(ad[r] * INV_SQRT_C);
  }
}

__global__ __launch_bounds__(256) void node_pre_v(
    const float* __restrict__ feats,
    const float* __restrict__ W_up1, const float* __restrict__ W_skip1,
    _Float16* __restrict__ UPH, float* __restrict__ out_sc) {
  __shared__ float ls[16 * 384];
  const int n0 = blockIdx.x * 16;
  const int t = threadIdx.x;
  for (int f = t; f < 16 * 384; f += 256) {
    int r = f / 384, c = f % 384;
    ls[r * 384 + c] = feats[(size_t)(n0 + r) * 512 + 128 + c];
  }
  __syncthreads();
  int j = t & 127, g = t >> 7;
  float au[8][3], ak[8][3];
#pragma unroll
  for (int r = 0; r < 8; ++r)
#pragma unroll
    for (int c = 0; c < 3; ++c) { au[r][c] = 0.f; ak[r][c] = 0.f; }
  for (int i = 0; i < 128; ++i) {
    float wu = W_up1[(size_t)i * 128 + j];
    float wk = W_skip1[(size_t)i * 128 + j];
#pragma unroll
    for (int r = 0; r < 8; ++r) {
#pragma unroll
      for (int c = 0; c < 3; ++c) {
        float v = ls[(g * 8 + r) * 384 + i * 3 + c];
        au[r][c] += v * wu;
        ak[r][c] += v * wk;
      }
    }
  }
#pragma unroll
  for (int r = 0; r < 8; ++r) {
    int n = n0 + g * 8 + r;
#pragma unroll
    for (int c = 0; c < 3; ++c) {
      UPH[(size_t)n * 512 + 128 + j * 3 + c] = (_Float16)(au[r][c] * INV_SQRT_C);
      out_sc[(size_t)n * 512 + 128 + j * 3 + c] = ak[r][c] * INV_SQRT_C;
    }
  }
}

// ---------------------------------------------------------------------------
// CSR build (parameterized by edge_index column: 0=sender, 1=receiver).
// ---------------------------------------------------------------------------
__global__ void k_count(const int* __restrict__ edge_index, int* __restrict__ CNT,
                        int col) {
  int e = blockIdx.x * blockDim.x + threadIdx.x;
  if (e < NE) atomicAdd(&CNT[edge_index[e * 2 + col]], 1);
}

__global__ __launch_bounds__(1024) void k_scan(const int* __restrict__ CNT,
                                               int* __restrict__ OFF,
                                               int* __restrict__ CUR) {
  __shared__ int ts[1024];
  const int t = threadIdx.x;
  const int base = t * 10;
  int loc[10];
  int s = 0;
#pragma unroll
  for (int i = 0; i < 10; ++i) {
    int idx = base + i;
    int v = (idx < NN) ? CNT[idx] : 0;
    loc[i] = s;
    s += v;
  }
  ts[t] = s;
  __syncthreads();
  for (int off = 1; off < 1024; off <<= 1) {
    int v = (t >= off) ? ts[t - off] : 0;
    __syncthreads();
    ts[t] += v;
    __syncthreads();
  }
  int tp = (t > 0) ? ts[t - 1] : 0;
#pragma unroll
  for (int i = 0; i < 10; ++i) {
    int idx = base + i;
    if (idx < NN) {
      OFF[idx] = tp + loc[i];
      CUR[idx] = tp + loc[i];
    }
  }
  if (t == 1023) OFF[NN] = ts[1023];
}

__global__ void k_fill(const int* __restrict__ edge_index, int* __restrict__ CUR,
                       int* __restrict__ IDX, int col) {
  int e = blockIdx.x * blockDim.x + threadIdx.x;
  if (e < NE) {
    int r = edge_index[e * 2 + col];
    int pos = atomicAdd(&CUR[r], 1);
    IDX[pos] = e;
  }
}

// ---------------------------------------------------------------------------
// In-place MLP layer: full layer accumulated in registers, barrier once all
// reads of Buf are done, then overwrite Buf. Saves the 32 KB ping-pong buffer
// (LDS 64->48 KB => 3 blocks/CU instead of 2). Caller barriers after.
// ---------------------------------------------------------------------------
__device__ __forceinline__ void mlp_layer_ip(
    _Float16* Buf, const _Float16* __restrict__ Wz,
    int m, int g, int wv) {
  f32x4 acc[4][4];
  f32x4 zero4 = {0.f, 0.f, 0.f, 0.f};
#pragma unroll
  for (int rt = 0; rt < 4; ++rt)
#pragma unroll
    for (int ct = 0; ct < 4; ++ct) acc[rt][ct] = zero4;

#pragma unroll
  for (int kb = 0; kb < 8; ++kb) {
    f16x8 a[4], b[4];
#pragma unroll
    for (int rt = 0; rt < 4; ++rt) {
      int row = rt * 16 + m;
      a[rt] = *(const f16x8*)&Buf[row * 256 + (((kb * 2 + (g >> 1)) ^ m) << 4) + (g & 1) * 8];
    }
#pragma unroll
    for (int ct = 0; ct < 4; ++ct)
      b[ct] = *(const f16x8*)&Wz[((size_t)(kb * 256 + wv * 64 + ct * 16 + m) << 5) + g * 8];
#pragma unroll
    for (int rt = 0; rt < 4; ++rt)
#pragma unroll
      for (int ct = 0; ct < 4; ++ct)
        acc[rt][ct] = __builtin_amdgcn_mfma_f32_16x16x32_f16(a[rt], b[ct], acc[rt][ct], 0, 0, 0);
  }
  __syncthreads();  // all reads of Buf complete before in-place overwrite
#pragma unroll
  for (int rt = 0; rt < 4; ++rt)
#pragma unroll
    for (int q = 0; q < 4; ++q) {
      int row = rt * 16 + g * 4 + q;
      f16x4 pk;
#pragma unroll
      for (int ct = 0; ct < 4; ++ct) pk[ct] = (_Float16)silu_f(acc[rt][ct][q]);
      int blk = (wv * 4 + (m >> 2)) ^ (row & 15);
      *(f16x4*)&Buf[row * 256 + (blk << 4) + (m & 3) * 4] = pk;
    }
}

// ---------------------------------------------------------------------------
// Fused edge kernel — 64 edges/block, 256 threads (4 waves), sender-sorted
// order (SIDX). LDS 48 KB + staging => 3 blocks/CU.
//   - launch_bounds (256,2): empirically the 128-VGPR config (arg=3 forced
//     84 VGPRs => 580 MB scratch spill traffic, round-1 regression). 128
//     VGPRs still allows 12 waves/CU, so LDS remains the occupancy limiter
//     at 3 blocks/CU.
//   - MLP layers in place on HA; epilogue SW/SP merged into SWP (16 KB).
//   - plane loop writes A3c into HA (dead after last qgemm) so w3 stays in
//     SWP — no w3r register hoist (saves 16 VGPRs vs round 1).
//   - sched_barrier(0) after every sw_write whose values are read same-wave
//     cross-lane before the next __syncthreads: the compiler only tracks
//     per-thread LDS deps and may hoist those ds_reads above the ds_writes
//     (suspected cause of round-1 absmax 0.056).
// ---------------------------------------------------------------------------
__global__ __launch_bounds__(256, 2) void edge_mlp(
    const float* __restrict__ edge_attrs,
    const float* __restrict__ edge_feats,
    const int* __restrict__ edge_index,
    const int* __restrict__ SIDX,
    const _Float16* __restrict__ DOWNH,
    const _Float16* __restrict__ UPH,
    const _Float16* __restrict__ W0h, const _Float16* __restrict__ W1h,
    const _Float16* __restrict__ W2h, const _Float16* __restrict__ W3h,
    const _Float16* __restrict__ WL0h, const _Float16* __restrict__ WL1h,
    _Float16* __restrict__ MIDs) {
  __shared__ _Float16 HA[64 * 256];    // 32 KB — MLP in-place + h3; plane-loop scratch
  __shared__ _Float16 SWP[64 * 128];   // 16 KB — merged SW/SP scratch
  __shared__ int    SIDs[64];
  __shared__ float4 EAs[64];

  const int tid = threadIdx.x;
  const int lane = tid & 63;
  const int wv = tid >> 6;
  const int m = lane & 15;
  const int g = lane >> 4;
  const int e0 = blockIdx.x * 64;
  const int nw = wv * 64;

  // stage block edge ids + attrs (visible after the layer-0 barrier)
  if (tid < 64) {
    int el = SIDX[e0 + tid];
    SIDs[tid] = el;
    EAs[tid] = *(const float4*)&edge_attrs[(size_t)el * 4];
  }

  int el_r[4], snd_r[4], rcv_r[4];
#pragma unroll
  for (int rt = 0; rt < 4; ++rt) {
    el_r[rt] = SIDX[e0 + rt * 16 + m];
    int2 sr = *(const int2*)&edge_index[(size_t)el_r[rt] * 2];
    snd_r[rt] = sr.x;
    rcv_r[rt] = sr.y;
  }

  f32x4 zero4 = {0.f, 0.f, 0.f, 0.f};
  f16x8 zf = {0, 0, 0, 0, 0, 0, 0, 0};

  // ---------------- layer 0: aug(136, padded 160) -> h1 (HA)
  {
    f32x4 acc[4][4];
#pragma unroll
    for (int rt = 0; rt < 4; ++rt)
#pragma unroll
      for (int ct = 0; ct < 4; ++ct) acc[rt][ct] = zero4;

#pragma unroll
    for (int kb = 0; kb < 5; ++kb) {
      const int k0 = kb * 32 + g * 8;
      f16x8 a[4], b[4];
#pragma unroll
      for (int rt = 0; rt < 4; ++rt) {
        if (k0 == 0) {
          const float* ef = &edge_feats[(size_t)el_r[rt] * 8];
          float4 f0 = *(const float4*)ef;
          float4 f1 = *(const float4*)(ef + 4);
          f16x8 av;
          av[0] = (_Float16)f0.x; av[1] = (_Float16)f0.y;
          av[2] = (_Float16)f0.z; av[3] = (_Float16)f0.w;
          av[4] = (_Float16)f1.x; av[5] = (_Float16)f1.y;
          av[6] = (_Float16)f1.z; av[7] = (_Float16)f1.w;
          a[rt] = av;
        } else if (k0 < 72) {
          a[rt] = *(const f16x8*)&DOWNH[(size_t)snd_r[rt] * 64 + (k0 - 8)];
        } else if (k0 < 136) {
          a[rt] = *(const f16x8*)&DOWNH[(size_t)rcv_r[rt] * 64 + (k0 - 72)];
        } else {
          a[rt] = zf;
        }
      }
#pragma unroll
      for (int ct = 0; ct < 4; ++ct)
        b[ct] = *(const f16x8*)&W0h[((size_t)(kb * 256 + nw + ct * 16 + m) << 5) + g * 8];
#pragma unroll
      for (int rt = 0; rt < 4; ++rt)
#pragma unroll
        for (int ct = 0; ct < 4; ++ct)
          acc[rt][ct] = __builtin_amdgcn_mfma_f32_16x16x32_f16(a[rt], b[ct], acc[rt][ct], 0, 0, 0);
    }
#pragma unroll
    for (int rt = 0; rt < 4; ++rt)
#pragma unroll
      for (int q = 0; q < 4; ++q) {
        int row = rt * 16 + g * 4 + q;
        f16x4 pk;
#pragma unroll
        for (int ct = 0; ct < 4; ++ct) pk[ct] = (_Float16)silu_f(acc[rt][ct][q]);
        int blk = (wv * 4 + (m >> 2)) ^ (row & 15);
        *(f16x4*)&HA[row * 256 + (blk << 4) + (m & 3) * 4] = pk;
      }
  }
  __syncthreads();

  mlp_layer_ip(HA, W1h, m, g, wv);   // layer 1: h1 -> h2 (in place)
  __syncthreads();
  mlp_layer_ip(HA, W2h, m, g, wv);   // layer 2: h2 -> h3 (in place)
  __syncthreads();
  // HA = h3, read-only until the plane loop reuses it as scratch.

  // ================= epilogue =================
  const int e_loc = lane;
  const int ers = (e_loc ^ (e_loc >> 3)) & 7;
  const int elc = SIDs[e_loc];
  const int snd_e = edge_index[(size_t)elc * 2];
  const _Float16* uprow = &UPH[(size_t)snd_e * 512];

  // quarter GEMM into caller-provided acc buffer (reads HA only)
  auto qgemm = [&](int qbase, f32x4 (&accq)[4][2]) {
#pragma unroll
    for (int rt = 0; rt < 4; ++rt)
#pragma unroll
      for (int ct = 0; ct < 2; ++ct) accq[rt][ct] = zero4;
#pragma unroll
    for (int kb = 0; kb < 8; ++kb) {
      f16x8 a[4], b[2];
#pragma unroll
      for (int rt = 0; rt < 4; ++rt) {
        int row = rt * 16 + m;
        a[rt] = *(const f16x8*)&HA[row * 256 + (((kb * 2 + (g >> 1)) ^ m) << 4) + (g & 1) * 8];
      }
#pragma unroll
      for (int ct = 0; ct < 2; ++ct)
        b[ct] = *(const f16x8*)&W3h[((size_t)(kb * 512 + qbase + wv * 32 + ct * 16 + m) << 5) + g * 8];
#pragma unroll
      for (int rt = 0; rt < 4; ++rt)
#pragma unroll
        for (int ct = 0; ct < 2; ++ct)
          accq[rt][ct] = __builtin_amdgcn_mfma_f32_16x16x32_f16(a[rt], b[ct], accq[rt][ct], 0, 0, 0);
    }
  };

  auto sw_write = [&](const f32x4 (&accq)[4][2]) {
#pragma unroll
    for (int rt = 0; rt < 4; ++rt)
#pragma unroll
      for (int r4 = 0; r4 < 4; ++r4) {
        int row = rt * 16 + g * 4 + r4;
        int rs = (row ^ (row >> 3)) & 7;
        f16x2 pk;
        pk[0] = (_Float16)accq[rt][0][r4];
        pk[1] = (_Float16)accq[rt][1][r4];
        int blk = ((wv * 2 + (m >> 3)) ^ rs) & 7;
        *(f16x2*)&SWP[row * 128 + (blk << 4) + (m & 7) * 2] = pk;
      }
  };

  // fold from an arbitrary 64x128 swizzled A-buffer
  auto fold = [&](const _Float16* Abuf, const _Float16* __restrict__ WLh,
                  int qpart, f32x4 (&P)[4][2]) {
#pragma unroll
    for (int rt = 0; rt < 4; ++rt)
#pragma unroll
      for (int ct = 0; ct < 2; ++ct) P[rt][ct] = zero4;
#pragma unroll
    for (int kb = 0; kb < 4; ++kb) {
      f16x8 a[4], b[2];
#pragma unroll
      for (int rt = 0; rt < 4; ++rt) {
        int row = rt * 16 + m;
        int rs = (row ^ (row >> 3)) & 7;
        a[rt] = *(const f16x8*)&Abuf[row * 128 + ((((kb * 2 + (g >> 1)) ^ rs) & 7) << 4) + (g & 1) * 8];
      }
#pragma unroll
      for (int ct = 0; ct < 2; ++ct)
        b[ct] = *(const f16x8*)&WLh[((size_t)((qpart * 4 + kb) * 128 + wv * 32 + ct * 16 + m) << 5) + g * 8];
#pragma unroll
      for (int rt = 0; rt < 4; ++rt)
#pragma unroll
        for (int ct = 0; ct < 2; ++ct)
          P[rt][ct] = __builtin_amdgcn_mfma_f32_16x16x32_f16(a[rt], b[ct], P[rt][ct], 0, 0, 0);
    }
  };

  // in-place: each thread reads ONLY the 4 f16x8 slots it writes back
  auto tp_xs = [&]() {
#pragma unroll
    for (int cch = 0; cch < 4; ++cch) {
      int ib = nw / 2 + cch * 8;
      int blk = ((ib >> 4) ^ ers) & 7;
      int off = e_loc * 128 + (blk << 4) + (ib & 15);
      f16x8 swv = *(const f16x8*)&SWP[off];
      f16x8 upv = *(const f16x8*)&uprow[ib];
      f16x8 pr = swv * upv;
      *(f16x8*)&SWP[off] = pr;
    }
  };

  _Float16 xvb[96];
  auto load_xv = [&]() {
#pragma unroll
    for (int u = 0; u < 12; ++u) {
      f16x8 t = *(const f16x8*)&uprow[128 + wv * 96 + u * 8];
#pragma unroll
      for (int z = 0; z < 8; ++z) xvb[u * 8 + z] = t[z];
    }
  };

  auto tp_w4 = [&]() {
    float4 ea = EAs[e_loc];
#pragma unroll
    for (int cch = 0; cch < 4; ++cch) {
      int ib = nw / 2 + cch * 8;
      int blk = ((ib >> 4) ^ ers) & 7;
      int off = e_loc * 128 + (blk << 4) + (ib & 15);
      f16x8 swv = *(const f16x8*)&SWP[off];
      f16x8 outv;
#pragma unroll
      for (int z = 0; z < 8; ++z) {
        int k = cch * 8 + z;
        float d = (float)xvb[k * 3] * ea.y + (float)xvb[k * 3 + 1] * ea.z +
                  (float)xvb[k * 3 + 2] * ea.w;
        outv[z] = (_Float16)((float)swv[z] * d);
      }
      *(f16x8*)&SWP[off] = outv;
    }
  };

  f32x4 accqA[4][2], accqB[4][2];
  f32x4 P1[4][2], P4[4][2], P2[4][2], P3[4][2];

  // ---- q1 (w1): SWP <- w1 -> A1 (in place) ; P1 = A1 @ WL0a
  qgemm(0, accqA);
  sw_write(accqA);            // SWP <- w1  (wave-owned column blocks)
  __builtin_amdgcn_sched_barrier(0);  // pin ds_write->ds_read wave order
  tp_xs();                    // SWP: w1 -> A1 (same-wave columns, in place)
  qgemm(384, accqB);          // w4, independent — fills the barrier wait
  __syncthreads();            // B1: A1 complete (all waves)
  fold(SWP, WL0h, 0, P1);     // cross-wave read of SWP(A1)
  load_xv();
  __syncthreads();            // B2: folds done reading A1
  sw_write(accqB);            // SWP <- w4
  __builtin_amdgcn_sched_barrier(0);
  tp_w4();                    // SWP: w4 -> A4 (same-wave, in place)
  qgemm(128, accqA);          // w2 queued
  __syncthreads();            // B3: A4 complete
  fold(SWP, WL0h, 1, P4);
  __syncthreads();            // B4: folds done reading A4
  sw_write(accqA);            // SWP <- w2
  __builtin_amdgcn_sched_barrier(0);
  tp_xs();                    // SWP: w2 -> A2 (same-wave, in place)
  qgemm(256, accqB);          // w3 queued (last reader of HA)

  // scalar part: MIDs[:, j] = y0*P1 + P4/sqrt(3)  (global only — overlaps)
#pragma unroll
  for (int rt = 0; rt < 4; ++rt)
#pragma unroll
    for (int r4 = 0; r4 < 4; ++r4) {
      int row = rt * 16 + g * 4 + r4;
      int elw = SIDs[row];
      float4 ea = EAs[row];
      f16x2 pk;
      pk[0] = (_Float16)(ea.x * P1[rt][0][r4] + INV_SQRT3F * P4[rt][0][r4]);
      pk[1] = (_Float16)(ea.x * P1[rt][1][r4] + INV_SQRT3F * P4[rt][1][r4]);
      *(f16x2*)&MIDs[(size_t)elw * 512 + wv * 32 + m * 2] = pk;
    }
  __syncthreads();            // B5: A2 complete
  fold(SWP, WL1h, 0, P2);
  __syncthreads();            // B6: folds done reading A2; HA now dead
  sw_write(accqB);            // SWP <- w3 (stays intact through plane loop)
  __builtin_amdgcn_sched_barrier(0);

  // plane loop: A3c goes into HA scratch (HA dead after qgemm(256)); w3
  // re-read from SWP each plane — no register hoist needed.
  _Float16* HSC = HA;
#pragma unroll
  for (int c = 0; c < 3; ++c) {
#pragma unroll
    for (int cch = 0; cch < 4; ++cch) {
      int ib = nw / 2 + cch * 8;
      int blk = ((ib >> 4) ^ ers) & 7;
      int off = e_loc * 128 + (blk << 4) + (ib & 15);
      f16x8 w3v = *(const f16x8*)&SWP[off];   // same-wave dep on sw_write above
      f16x8 outv;
#pragma unroll
      for (int z = 0; z < 8; ++z)
        outv[z] = w3v[z] * xvb[(cch * 8 + z) * 3 + c];
      *(f16x8*)&HSC[off] = outv;
    }
    __syncthreads();          // A3c complete
    fold(HSC, WL1h, 1, P3);
    // plane c: MIDs[:, 128 + c*128 + j] = yv[c]*P2 + y0*P3
#pragma unroll
    for (int rt = 0; rt < 4; ++rt)
#pragma unroll
      for (int r4 = 0; r4 < 4; ++r4) {
        int row = rt * 16 + g * 4 + r4;
        int elw = SIDs[row];
        float4 ea = EAs[row];
        float yvc = (c == 0) ? ea.y : (c == 1) ? ea.z : ea.w;
        f16x2 pk;
        pk[0] = (_Float16)(yvc * P2[rt][0][r4] + ea.x * P3[rt][0][r4]);
        pk[1] = (_Float16)(yvc * P2[rt][1][r4] + ea.x * P3[rt][1][r4]);
        *(f16x2*)&MIDs[(size_t)elw * 512 + 128 + c * 128 + wv * 32 + m * 2] = pk;
      }
    if (c < 2) __syncthreads();  // folds done reading A3c before next write
  }
}

// ---------------------------------------------------------------------------
// Gather: one block per node; LDS-staged edge ids + 4-way unroll; output row
// staged in LDS and stored coalesced (float2/lane) instead of 4-strided.
// ---------------------------------------------------------------------------
__global__ __launch_bounds__(256) void gather_msg(
    const _Float16* __restrict__ MIDs, const int* __restrict__ OFF,
    const int* __restrict__ EIDX, float* __restrict__ out) {
  __shared__ int eb[256];
  __shared__ float os[512];
  const int n = blockIdx.x;
  const int t = threadIdx.x;
  const int beg = OFF[n], end = OFF[n + 1];
  float a0 = 0.f, a1 = 0.f;
  for (int base = beg; base < end; base += 256) {
    int cnt = min(256, end - base);
    __syncthreads();
    if (t < cnt) eb[t] = EIDX[base + t];
    __syncthreads();
    int k = 0;
    for (; k + 4 <= cnt; k += 4) {
      int e0_ = eb[k], e1_ = eb[k + 1], e2_ = eb[k + 2], e3_ = eb[k + 3];
      f16x2 v0 = *(const f16x2*)&MIDs[(size_t)e0_ * 512 + t * 2];
      f16x2 v1 = *(const f16x2*)&MIDs[(size_t)e1_ * 512 + t * 2];
      f16x2 v2 = *(const f16x2*)&MIDs[(size_t)e2_ * 512 + t * 2];
      f16x2 v3 = *(const f16x2*)&MIDs[(size_t)e3_ * 512 + t * 2];
      a0 += (float)v0[0] + (float)v1[0] + (float)v2[0] + (float)v3[0];
      a1 += (float)v0[1] + (float)v1[1] + (float)v2[1] + (float)v3[1];
    }
    for (; k < cnt; ++k) {
      f16x2 v = *(const f16x2*)&MIDs[(size_t)eb[k] * 512 + t * 2];
      a0 += (float)v[0];
      a1 += (float)v[1];
    }
  }
#pragma unroll
  for (int u = 0; u < 2; ++u) {
    int x = t * 2 + u;
    float a = u ? a1 : a0;
    int dst;
    if (x < 128) {
      dst = x * 4;
    } else {
      int xm = x - 128;
      int c = xm >> 7, j = xm & 127;
      dst = j * 4 + 1 + c;
    }
    os[dst] = a;
  }
  __syncthreads();
  *(float2*)&out[(size_t)n * 512 + t * 2] = *(const float2*)&os[t * 2];
}

// ---------------------------------------------------------------------------
extern "C" void kernel_launch(void* const* d_in, const int* in_sizes, int n_in,
                              void* d_out, int out_size, void* d_ws, size_t ws_size,
                              hipStream_t stream) {
  const float* node_feats = (const float*)d_in[1];
  const float* edge_attrs = (const float*)d_in[2];
  const float* edge_feats = (const float*)d_in[3];
  const int*   edge_index = (const int*)d_in[4];
  const float* W_up0   = (const float*)d_in[5];
  const float* W_up1   = (const float*)d_in[6];
  const float* W_down  = (const float*)d_in[7];
  const float* Wm0     = (const float*)d_in[8];
  const float* Wm1     = (const float*)d_in[9];
  const float* Wm2     = (const float*)d_in[10];
  const float* Wm3     = (const float*)d_in[11];
  const float* W_lin0  = (const float*)d_in[12];
  const float* W_lin1  = (const float*)d_in[13];
  const float* W_skip0 = (const float*)d_in[14];
  const float* W_skip1 = (const float*)d_in[15];
  float* out = (float*)d_out;

  char* ws = (char*)d_ws;
  size_t off = 0;
  auto alloc = [&](size_t bytes) {
    void* p = ws + off;
    off = (off + bytes + 255) & ~(size_t)255;
    return p;
  };
  _Float16* UPH   = (_Float16*)alloc((size_t)NN * 512 * 2);
  _Float16* DOWNH = (_Float16*)alloc((size_t)NN * 64 * 2);
  _Float16* W0h   = (_Float16*)alloc(160 * 256 * 2);
  _Float16* W1h   = (_Float16*)alloc(256 * 256 * 2);
  _Float16* W2h   = (_Float16*)alloc(256 * 256 * 2);
  _Float16* W3h   = (_Float16*)alloc(256 * 512 * 2);
  _Float16* WL0h  = (_Float16*)alloc(256 * 128 * 2);
  _Float16* WL1h  = (_Float16*)alloc(256 * 128 * 2);
  int*      CNT   = (int*)alloc((size_t)NN * 4);
  int*      OFF   = (int*)alloc((size_t)(NN + 1) * 4);
  int*      CUR   = (int*)alloc((size_t)NN * 4);
  int*      EIDX  = (int*)alloc((size_t)NE * 4);
  int*      CNT2  = (int*)alloc((size_t)NN * 4);
  int*      OFF2  = (int*)alloc((size_t)(NN + 1) * 4);
  int*      CUR2  = (int*)alloc((size_t)NN * 4);
  int*      SIDX  = (int*)alloc((size_t)NE * 4);
  _Float16* MIDs  = (_Float16*)alloc((size_t)NE * 512 * 2);

  hipMemsetAsync(CNT, 0, (size_t)NN * 4, stream);
  hipMemsetAsync(CNT2, 0, (size_t)NN * 4, stream);

  // scales folded into fp16 weights: 1/sqrt(136) layer0, 1/16 layers 1..3,
  // 1/256 for W_lin (includes sqrt(2C) and AVG_NEIGH)
  wconv<<<160, 256, 0, stream>>>(Wm0, W0h, 136, 160, 256, 1.0f / sqrtf(136.0f), 64);
  wconv<<<256, 256, 0, stream>>>(Wm1, W1h, 256, 256, 256, 0.0625f, 64);
  wconv<<<256, 256, 0, stream>>>(Wm2, W2h, 256, 256, 256, 0.0625f, 64);
  wconv<<<512, 256, 0, stream>>>(Wm3, W3h, 256, 256, 512, 0.0625f, 32);
  wconv<<<128, 256, 0, stream>>>(W_lin0, WL0h, 256, 256, 128, 1.0f / 256.0f, 32);
  wconv<<<128, 256, 0, stream>>>(W_lin1, WL1h, 256, 256, 128, 1.0f / 256.0f, 32);

  node_pre_s<<<625, 256, 0, stream>>>(node_feats, W_up0, W_skip0, W_down,
                                      UPH, DOWNH, out + (size_t)NN * 512);
  node_pre_v<<<625, 256, 0, stream>>>(node_feats, W_up1, W_skip1,
                                      UPH, out + (size_t)NN * 512);

  // receiver CSR (gather) + sender CSR (edge processing order)
  k_count<<<625, 256, 0, stream>>>(edge_index, CNT, 1);
  k_count<<<625, 256, 0, stream>>>(edge_index, CNT2, 0);
  k_scan<<<1, 1024, 0, stream>>>(CNT, OFF, CUR);
  k_scan<<<1, 1024, 0, stream>>>(CNT2, OFF2, CUR2);
  k_fill<<<625, 256, 0, stream>>>(edge_index, CUR, EIDX, 1);
  k_fill<<<625, 256, 0, stream>>>(edge_index, CUR2, SIDX, 0);

  edge_mlp<<<2500, 256, 0, stream>>>(edge_attrs, edge_feats, edge_index, SIDX,
                                     DOWNH, UPH, W0h, W1h, W2h, W3h, WL0h, WL1h,
                                     MIDs);
  gather_msg<<<NN, 256, 0, stream>>>(MIDs, OFF, EIDX, out);
}

// Round 3
// 551.735 us; speedup vs baseline: 1.1520x; 1.1042x over previous
//
#include <hip/hip_runtime.h>
#include <cmath>

#define NN 10000
#define NE 160000
#define INV_SQRT_C 0.08838834764831845f   // 1/sqrt(128)
#define INV_SQRT3F 0.5773502691896258f

typedef _Float16 f16x8 __attribute__((ext_vector_type(8)));
typedef _Float16 f16x4 __attribute__((ext_vector_type(4)));
typedef _Float16 f16x2 __attribute__((ext_vector_type(2)));
typedef float    f32x4 __attribute__((ext_vector_type(4)));

__device__ __forceinline__ float silu_f(float x) {
  return x / (1.f + __expf(-x));
}

// ---------------------------------------------------------------------------
// Weight conversion fp32 -> fp16, B-fragment swizzle + column permutation
// (storage slot ct*16+m within a P-chunk holds logical col m*(P/16)+ct).
// ---------------------------------------------------------------------------
__global__ void wconv(const float* __restrict__ src, _Float16* __restrict__ dst,
                      int Korig, int Kpad, int N, float scale, int P) {
  int total = Kpad * N;
  for (int t = blockIdx.x * blockDim.x + threadIdx.x; t < total;
       t += gridDim.x * blockDim.x) {
    int n = t % N;
    int k = t / N;
    int kb = k >> 5, kk = k & 31;
    int sub = n & (P - 1);
    int n_l = (n & ~(P - 1)) | ((sub & 15) * (P >> 4) + (sub >> 4));
    float v = (k < Korig) ? src[(size_t)k * N + n_l] * scale : 0.f;
    dst[((size_t)(kb * N + n) << 5) + kk] = (_Float16)v;
  }
}

// ---------------------------------------------------------------------------
// Node pre-pass, fused: pass 0 (s-tile): up_s, sc_s, down. pass 1 (v-tile):
// up_v, sc_v. Same arithmetic as the verified 5-pass version.
// ---------------------------------------------------------------------------
__global__ __launch_bounds__(256) void node_pre_s(
    const float* __restrict__ feats,
    const float* __restrict__ W_up0, const float* __restrict__ W_skip0,
    const float* __restrict__ W_down,
    _Float16* __restrict__ UPH, _Float16* __restrict__ DOWNH,
    float* __restrict__ out_sc) {
  __shared__ float ls[16 * 128];
  const int n0 = blockIdx.x * 16;
  const int t = threadIdx.x;
  for (int f = t; f < 16 * 128; f += 256) {
    int r = f >> 7, c = f & 127;
    ls[r * 128 + c] = feats[(size_t)(n0 + r) * 512 + c];
  }
  __syncthreads();
  {
    int j = t & 127, g = t >> 7;  // 8 nodes per group
    float au[8] = {0, 0, 0, 0, 0, 0, 0, 0};
    float ak[8] = {0, 0, 0, 0, 0, 0, 0, 0};
    for (int i = 0; i < 128; ++i) {
      float wu = W_up0[(size_t)i * 128 + j];
      float wk = W_skip0[(size_t)i * 128 + j];
#pragma unroll
      for (int r = 0; r < 8; ++r) {
        float s = ls[(g * 8 + r) * 128 + i];
        au[r] += s * wu;
        ak[r] += s * wk;
      }
    }
#pragma unroll
    for (int r = 0; r < 8; ++r) {
      int n = n0 + g * 8 + r;
      UPH[(size_t)n * 512 + j] = (_Float16)(au[r] * INV_SQRT_C);
      out_sc[(size_t)n * 512 + j] = ak[r] * INV_SQRT_C;
    }
  }
  {
    int j = t & 63, g = t >> 6;  // 4 nodes per group
    float ad[4] = {0, 0, 0, 0};
    for (int i = 0; i < 128; ++i) {
      float wd = W_down[(size_t)i * 64 + j];
#pragma unroll
      for (int r = 0; r < 4; ++r) ad[r] += ls[(g * 4 + r) * 128 + i] * wd;
    }
#pragma unroll
    for (int r = 0; r < 4; ++r)
      DOWNH[(size_t)(n0 + g * 4 + r) * 64 + j] = (_Float16)(ad[r] * INV_SQRT_C);
  }
}

__global__ __launch_bounds__(256) void node_pre_v(
    const float* __restrict__ feats,
    const float* __restrict__ W_up1, const float* __restrict__ W_skip1,
    _Float16* __restrict__ UPH, float* __restrict__ out_sc) {
  __shared__ float ls[16 * 384];
  const int n0 = blockIdx.x * 16;
  const int t = threadIdx.x;
  for (int f = t; f < 16 * 384; f += 256) {
    int r = f / 384, c = f % 384;
    ls[r * 384 + c] = feats[(size_t)(n0 + r) * 512 + 128 + c];
  }
  __syncthreads();
  int j = t & 127, g = t >> 7;
  float au[8][3], ak[8][3];
#pragma unroll
  for (int r = 0; r < 8; ++r)
#pragma unroll
    for (int c = 0; c < 3; ++c) { au[r][c] = 0.f; ak[r][c] = 0.f; }
  for (int i = 0; i < 128; ++i) {
    float wu = W_up1[(size_t)i * 128 + j];
    float wk = W_skip1[(size_t)i * 128 + j];
#pragma unroll
    for (int r = 0; r < 8; ++r) {
#pragma unroll
      for (int c = 0; c < 3; ++c) {
        float v = ls[(g * 8 + r) * 384 + i * 3 + c];
        au[r][c] += v * wu;
        ak[r][c] += v * wk;
      }
    }
  }
#pragma unroll
  for (int r = 0; r < 8; ++r) {
    int n = n0 + g * 8 + r;
#pragma unroll
    for (int c = 0; c < 3; ++c) {
      UPH[(size_t)n * 512 + 128 + j * 3 + c] = (_Float16)(au[r][c] * INV_SQRT_C);
      out_sc[(size_t)n * 512 + 128 + j * 3 + c] = ak[r][c] * INV_SQRT_C;
    }
  }
}

// ---------------------------------------------------------------------------
// CSR build (parameterized by edge_index column: 0=sender, 1=receiver).
// ---------------------------------------------------------------------------
__global__ void k_count(const int* __restrict__ edge_index, int* __restrict__ CNT,
                        int col) {
  int e = blockIdx.x * blockDim.x + threadIdx.x;
  if (e < NE) atomicAdd(&CNT[edge_index[e * 2 + col]], 1);
}

__global__ __launch_bounds__(1024) void k_scan(const int* __restrict__ CNT,
                                               int* __restrict__ OFF,
                                               int* __restrict__ CUR) {
  __shared__ int ts[1024];
  const int t = threadIdx.x;
  const int base = t * 10;
  int loc[10];
  int s = 0;
#pragma unroll
  for (int i = 0; i < 10; ++i) {
    int idx = base + i;
    int v = (idx < NN) ? CNT[idx] : 0;
    loc[i] = s;
    s += v;
  }
  ts[t] = s;
  __syncthreads();
  for (int off = 1; off < 1024; off <<= 1) {
    int v = (t >= off) ? ts[t - off] : 0;
    __syncthreads();
    ts[t] += v;
    __syncthreads();
  }
  int tp = (t > 0) ? ts[t - 1] : 0;
#pragma unroll
  for (int i = 0; i < 10; ++i) {
    int idx = base + i;
    if (idx < NN) {
      OFF[idx] = tp + loc[i];
      CUR[idx] = tp + loc[i];
    }
  }
  if (t == 1023) OFF[NN] = ts[1023];
}

__global__ void k_fill(const int* __restrict__ edge_index, int* __restrict__ CUR,
                       int* __restrict__ IDX, int col) {
  int e = blockIdx.x * blockDim.x + threadIdx.x;
  if (e < NE) {
    int r = edge_index[e * 2 + col];
    int pos = atomicAdd(&CUR[r], 1);
    IDX[pos] = e;
  }
}

// ---------------------------------------------------------------------------
// Fused edge kernel — round-0 verified structure (HA/HB ping-pong, SW/SP
// separate, original barrier schedule; 64 KB LDS, 2 blocks/CU, 128 VGPR,
// absmax 0.002). Additions this round, both correctness-neutral:
//   1. s_setprio(1/0) around each MFMA cluster (T5): with 2 independent
//      blocks/CU at different phases, favors the MFMA-issuing wave over
//      waves doing staging/barrier spin.
//   2. bijective XCD swizzle of blockIdx (T1/m204): sender-sorted edges mean
//      consecutive blocks share UPH/DOWNH panels; give each XCD a contiguous
//      run of blocks for L2 reuse. 2500 = 8*312+4, handled bijectively.
// ---------------------------------------------------------------------------
__device__ __forceinline__ void mlp_layer_256(
    const _Float16* In, _Float16* Out, const _Float16* __restrict__ Wz,
    int m, int g, int wv) {
  f32x4 acc[4][4];
  f32x4 zero4 = {0.f, 0.f, 0.f, 0.f};
#pragma unroll
  for (int rt = 0; rt < 4; ++rt)
#pragma unroll
    for (int ct = 0; ct < 4; ++ct) acc[rt][ct] = zero4;

#pragma unroll
  for (int kb = 0; kb < 8; ++kb) {
    f16x8 a[4], b[4];
#pragma unroll
    for (int rt = 0; rt < 4; ++rt) {
      int row = rt * 16 + m;
      a[rt] = *(const f16x8*)&In[row * 256 + (((kb * 2 + (g >> 1)) ^ m) << 4) + (g & 1) * 8];
    }
#pragma unroll
    for (int ct = 0; ct < 4; ++ct)
      b[ct] = *(const f16x8*)&Wz[((size_t)(kb * 256 + wv * 64 + ct * 16 + m) << 5) + g * 8];
    __builtin_amdgcn_s_setprio(1);
#pragma unroll
    for (int rt = 0; rt < 4; ++rt)
#pragma unroll
      for (int ct = 0; ct < 4; ++ct)
        acc[rt][ct] = __builtin_amdgcn_mfma_f32_16x16x32_f16(a[rt], b[ct], acc[rt][ct], 0, 0, 0);
    __builtin_amdgcn_s_setprio(0);
  }
#pragma unroll
  for (int rt = 0; rt < 4; ++rt)
#pragma unroll
    for (int q = 0; q < 4; ++q) {
      int row = rt * 16 + g * 4 + q;
      f16x4 pk;
#pragma unroll
      for (int ct = 0; ct < 4; ++ct) pk[ct] = (_Float16)silu_f(acc[rt][ct][q]);
      int blk = (wv * 4 + (m >> 2)) ^ (row & 15);
      *(f16x4*)&Out[row * 256 + (blk << 4) + (m & 3) * 4] = pk;
    }
}

__global__ __launch_bounds__(256, 2) void edge_mlp(
    const float* __restrict__ edge_attrs,
    const float* __restrict__ edge_feats,
    const int* __restrict__ edge_index,
    const int* __restrict__ SIDX,
    const _Float16* __restrict__ DOWNH,
    const _Float16* __restrict__ UPH,
    const _Float16* __restrict__ W0h, const _Float16* __restrict__ W1h,
    const _Float16* __restrict__ W2h, const _Float16* __restrict__ W3h,
    const _Float16* __restrict__ WL0h, const _Float16* __restrict__ WL1h,
    _Float16* __restrict__ MIDs) {
  __shared__ _Float16 HA[64 * 256];
  __shared__ _Float16 HB[64 * 256];

  const int tid = threadIdx.x;
  const int lane = tid & 63;
  const int wv = tid >> 6;
  const int m = lane & 15;
  const int g = lane >> 4;

  // bijective XCD swizzle (m204): NB=2500, 8 XCDs, q=312, r=4.
  const int bid = blockIdx.x;
  const int xcd = bid & 7;
  const int idx = bid >> 3;
  const int bswz = (xcd < 4) ? (xcd * 313 + idx) : (4 * 313 + (xcd - 4) * 312 + idx);
  const int e0 = bswz * 64;
  const int nw = wv * 64;

  int el_r[4], snd_r[4], rcv_r[4];
#pragma unroll
  for (int rt = 0; rt < 4; ++rt) {
    el_r[rt] = SIDX[e0 + rt * 16 + m];
    int2 sr = *(const int2*)&edge_index[(size_t)el_r[rt] * 2];
    snd_r[rt] = sr.x;
    rcv_r[rt] = sr.y;
  }

  f32x4 zero4 = {0.f, 0.f, 0.f, 0.f};
  f16x8 zf = {0, 0, 0, 0, 0, 0, 0, 0};

  // ---------------- layer 0: aug(136, padded 160) -> h1 (HA)
  {
    f32x4 acc[4][4];
#pragma unroll
    for (int rt = 0; rt < 4; ++rt)
#pragma unroll
      for (int ct = 0; ct < 4; ++ct) acc[rt][ct] = zero4;

#pragma unroll
    for (int kb = 0; kb < 5; ++kb) {
      const int k0 = kb * 32 + g * 8;
      f16x8 a[4], b[4];
#pragma unroll
      for (int rt = 0; rt < 4; ++rt) {
        if (k0 == 0) {
          const float* ef = &edge_feats[(size_t)el_r[rt] * 8];
          float4 f0 = *(const float4*)ef;
          float4 f1 = *(const float4*)(ef + 4);
          f16x8 av;
          av[0] = (_Float16)f0.x; av[1] = (_Float16)f0.y;
          av[2] = (_Float16)f0.z; av[3] = (_Float16)f0.w;
          av[4] = (_Float16)f1.x; av[5] = (_Float16)f1.y;
          av[6] = (_Float16)f1.z; av[7] = (_Float16)f1.w;
          a[rt] = av;
        } else if (k0 < 72) {
          a[rt] = *(const f16x8*)&DOWNH[(size_t)snd_r[rt] * 64 + (k0 - 8)];
        } else if (k0 < 136) {
          a[rt] = *(const f16x8*)&DOWNH[(size_t)rcv_r[rt] * 64 + (k0 - 72)];
        } else {
          a[rt] = zf;
        }
      }
#pragma unroll
      for (int ct = 0; ct < 4; ++ct)
        b[ct] = *(const f16x8*)&W0h[((size_t)(kb * 256 + nw + ct * 16 + m) << 5) + g * 8];
      __builtin_amdgcn_s_setprio(1);
#pragma unroll
      for (int rt = 0; rt < 4; ++rt)
#pragma unroll
        for (int ct = 0; ct < 4; ++ct)
          acc[rt][ct] = __builtin_amdgcn_mfma_f32_16x16x32_f16(a[rt], b[ct], acc[rt][ct], 0, 0, 0);
      __builtin_amdgcn_s_setprio(0);
    }
#pragma unroll
    for (int rt = 0; rt < 4; ++rt)
#pragma unroll
      for (int q = 0; q < 4; ++q) {
        int row = rt * 16 + g * 4 + q;
        f16x4 pk;
#pragma unroll
        for (int ct = 0; ct < 4; ++ct) pk[ct] = (_Float16)silu_f(acc[rt][ct][q]);
        int blk = (wv * 4 + (m >> 2)) ^ (row & 15);
        *(f16x4*)&HA[row * 256 + (blk << 4) + (m & 3) * 4] = pk;
      }
  }
  __syncthreads();

  mlp_layer_256(HA, HB, W1h, m, g, wv);   // layer 1: h1 -> h2
  __syncthreads();
  mlp_layer_256(HB, HA, W2h, m, g, wv);   // layer 2: h2 -> h3 (HA stays live)
  __syncthreads();

  // ================= epilogue =================
  _Float16* SW = HB;             // 64 x 128 fp16, tpw quarter
  _Float16* SP = HB + 64 * 128;  // 64 x 128 fp16, TP'd A-matrix

  const int e_loc = lane;
  const int ers = (e_loc ^ (e_loc >> 3)) & 7;
  const int elc = SIDX[e0 + e_loc];
  const int snd_e = edge_index[(size_t)elc * 2];
  const _Float16* uprow = &UPH[(size_t)snd_e * 512];

  // quarter GEMM into caller-provided acc buffer
  auto qgemm = [&](int qbase, f32x4 (&accq)[4][2]) {
#pragma unroll
    for (int rt = 0; rt < 4; ++rt)
#pragma unroll
      for (int ct = 0; ct < 2; ++ct) accq[rt][ct] = zero4;
#pragma unroll
    for (int kb = 0; kb < 8; ++kb) {
      f16x8 a[4], b[2];
#pragma unroll
      for (int rt = 0; rt < 4; ++rt) {
        int row = rt * 16 + m;
        a[rt] = *(const f16x8*)&HA[row * 256 + (((kb * 2 + (g >> 1)) ^ m) << 4) + (g & 1) * 8];
      }
#pragma unroll
      for (int ct = 0; ct < 2; ++ct)
        b[ct] = *(const f16x8*)&W3h[((size_t)(kb * 512 + qbase + wv * 32 + ct * 16 + m) << 5) + g * 8];
      __builtin_amdgcn_s_setprio(1);
#pragma unroll
      for (int rt = 0; rt < 4; ++rt)
#pragma unroll
        for (int ct = 0; ct < 2; ++ct)
          accq[rt][ct] = __builtin_amdgcn_mfma_f32_16x16x32_f16(a[rt], b[ct], accq[rt][ct], 0, 0, 0);
      __builtin_amdgcn_s_setprio(0);
    }
  };

  auto sw_write = [&](const f32x4 (&accq)[4][2]) {
#pragma unroll
    for (int rt = 0; rt < 4; ++rt)
#pragma unroll
      for (int r4 = 0; r4 < 4; ++r4) {
        int row = rt * 16 + g * 4 + r4;
        int rs = (row ^ (row >> 3)) & 7;
        f16x2 pk;
        pk[0] = (_Float16)accq[rt][0][r4];
        pk[1] = (_Float16)accq[rt][1][r4];
        int blk = ((wv * 2 + (m >> 3)) ^ rs) & 7;
        *(f16x2*)&SW[row * 128 + (blk << 4) + (m & 7) * 2] = pk;
      }
  };

  auto fold = [&](const _Float16* __restrict__ WLh, int qpart, f32x4 (&P)[4][2]) {
#pragma unroll
    for (int rt = 0; rt < 4; ++rt)
#pragma unroll
      for (int ct = 0; ct < 2; ++ct) P[rt][ct] = zero4;
#pragma unroll
    for (int kb = 0; kb < 4; ++kb) {
      f16x8 a[4], b[2];
#pragma unroll
      for (int rt = 0; rt < 4; ++rt) {
        int row = rt * 16 + m;
        int rs = (row ^ (row >> 3)) & 7;
        a[rt] = *(const f16x8*)&SP[row * 128 + ((((kb * 2 + (g >> 1)) ^ rs) & 7) << 4) + (g & 1) * 8];
      }
#pragma unroll
      for (int ct = 0; ct < 2; ++ct)
        b[ct] = *(const f16x8*)&WLh[((size_t)((qpart * 4 + kb) * 128 + wv * 32 + ct * 16 + m) << 5) + g * 8];
      __builtin_amdgcn_s_setprio(1);
#pragma unroll
      for (int rt = 0; rt < 4; ++rt)
#pragma unroll
        for (int ct = 0; ct < 2; ++ct)
          P[rt][ct] = __builtin_amdgcn_mfma_f32_16x16x32_f16(a[rt], b[ct], P[rt][ct], 0, 0, 0);
      __builtin_amdgcn_s_setprio(0);
    }
  };

  auto tp_xs = [&]() {
#pragma unroll
    for (int cch = 0; cch < 4; ++cch) {
      int ib = nw / 2 + cch * 8;
      int blk = ((ib >> 4) ^ ers) & 7;
      int off = e_loc * 128 + (blk << 4) + (ib & 15);
      f16x8 swv = *(const f16x8*)&SW[off];
      f16x8 upv = *(const f16x8*)&uprow[ib];
      f16x8 pr = swv * upv;
      *(f16x8*)&SP[off] = pr;
    }
  };

  _Float16 xvb[96];
  auto load_xv = [&]() {
#pragma unroll
    for (int u = 0; u < 12; ++u) {
      f16x8 t = *(const f16x8*)&uprow[128 + wv * 96 + u * 8];
#pragma unroll
      for (int z = 0; z < 8; ++z) xvb[u * 8 + z] = t[z];
    }
  };

  auto tp_w4 = [&]() {
    float4 ea = *(const float4*)&edge_attrs[(size_t)elc * 4];
#pragma unroll
    for (int cch = 0; cch < 4; ++cch) {
      int ib = nw / 2 + cch * 8;
      int blk = ((ib >> 4) ^ ers) & 7;
      int off = e_loc * 128 + (blk << 4) + (ib & 15);
      f16x8 swv = *(const f16x8*)&SW[off];
      f16x8 outv;
#pragma unroll
      for (int z = 0; z < 8; ++z) {
        int k = cch * 8 + z;
        float d = (float)xvb[k * 3] * ea.y + (float)xvb[k * 3 + 1] * ea.z +
                  (float)xvb[k * 3 + 2] * ea.w;
        outv[z] = (_Float16)((float)swv[z] * d);
      }
      *(f16x8*)&SP[off] = outv;
    }
  };

  auto tp_w3 = [&](int c) {
#pragma unroll
    for (int cch = 0; cch < 4; ++cch) {
      int ib = nw / 2 + cch * 8;
      int blk = ((ib >> 4) ^ ers) & 7;
      int off = e_loc * 128 + (blk << 4) + (ib & 15);
      f16x8 swv = *(const f16x8*)&SW[off];
      f16x8 outv;
#pragma unroll
      for (int z = 0; z < 8; ++z) {
        int k = cch * 8 + z;
        outv[z] = swv[z] * xvb[k * 3 + c];
      }
      *(f16x8*)&SP[off] = outv;
    }
  };

  f32x4 accqA[4][2], accqB[4][2];
  f32x4 P1[4][2], P4[4][2], P2[4][2], P3[4][2];

  // q1 (w1): A1 = w1 (x) xs ; P1 = A1 @ WL0a. Queue q4 gemm before barrier.
  qgemm(0, accqA);
  sw_write(accqA);
  tp_xs();
  qgemm(384, accqB);          // w4, independent — fills the barrier wait
  __syncthreads();            // B1: SP(A1) complete
  fold(WL0h, 0, P1);
  sw_write(accqB);            // SW <- w4 (SW(w1) readers all pre-B1)
  load_xv();
  __syncthreads();            // B2: all folds done reading SP(A1)
  tp_w4();
  qgemm(128, accqA);          // w2 queued
  __syncthreads();            // B3: SP(A4) complete
  fold(WL0h, 1, P4);
  sw_write(accqA);            // SW <- w2 (tp_w4 reads all pre-B3)

  // scalar part: MIDs[:, j] = y0*P1 + P4/sqrt(3)
#pragma unroll
  for (int rt = 0; rt < 4; ++rt)
#pragma unroll
    for (int r4 = 0; r4 < 4; ++r4) {
      int row = rt * 16 + g * 4 + r4;
      int elw = SIDX[e0 + row];
      float4 ea = *(const float4*)&edge_attrs[(size_t)elw * 4];
      f16x2 pk;
      pk[0] = (_Float16)(ea.x * P1[rt][0][r4] + INV_SQRT3F * P4[rt][0][r4]);
      pk[1] = (_Float16)(ea.x * P1[rt][1][r4] + INV_SQRT3F * P4[rt][1][r4]);
      *(f16x2*)&MIDs[(size_t)elw * 512 + wv * 32 + m * 2] = pk;
    }
  __syncthreads();            // B4: folds done reading SP(A4)
  tp_xs();                    // SP <- A2 (reads SW(w2), own wave, pre-B4)
  qgemm(256, accqB);          // w3 queued
  __syncthreads();            // B5: SP(A2) complete
  fold(WL1h, 0, P2);
  sw_write(accqB);            // SW <- w3 (tp_xs reads all pre-B5)
  __syncthreads();            // B6: folds done reading SP(A2)

#pragma unroll
  for (int c = 0; c < 3; ++c) {
    tp_w3(c);                 // SP <- A3c (reads SW(w3), own wave)
    __syncthreads();          // SP complete
    fold(WL1h, 1, P3);
    // plane c: MIDs[:, 128 + c*128 + j] = yv[c]*P2 + y0*P3
#pragma unroll
    for (int rt = 0; rt < 4; ++rt)
#pragma unroll
      for (int r4 = 0; r4 < 4; ++r4) {
        int row = rt * 16 + g * 4 + r4;
        int elw = SIDX[e0 + row];
        float4 ea = *(const float4*)&edge_attrs[(size_t)elw * 4];
        float yvc = (c == 0) ? ea.y : (c == 1) ? ea.z : ea.w;
        f16x2 pk;
        pk[0] = (_Float16)(yvc * P2[rt][0][r4] + ea.x * P3[rt][0][r4]);
        pk[1] = (_Float16)(yvc * P2[rt][1][r4] + ea.x * P3[rt][1][r4]);
        *(f16x2*)&MIDs[(size_t)elw * 512 + 128 + c * 128 + wv * 32 + m * 2] = pk;
      }
    if (c < 2) __syncthreads();  // folds done reading SP before next tp_w3
  }
}

// ---------------------------------------------------------------------------
// Gather: one block per node; LDS-staged edge ids + 4-way unroll; output row
// staged in LDS and stored coalesced (float2/lane) instead of 4-strided.
// ---------------------------------------------------------------------------
__global__ __launch_bounds__(256) void gather_msg(
    const _Float16* __restrict__ MIDs, const int* __restrict__ OFF,
    const int* __restrict__ EIDX, float* __restrict__ out) {
  __shared__ int eb[256];
  __shared__ float os[512];
  const int n = blockIdx.x;
  const int t = threadIdx.x;
  const int beg = OFF[n], end = OFF[n + 1];
  float a0 = 0.f, a1 = 0.f;
  for (int base = beg; base < end; base += 256) {
    int cnt = min(256, end - base);
    __syncthreads();
    if (t < cnt) eb[t] = EIDX[base + t];
    __syncthreads();
    int k = 0;
    for (; k + 4 <= cnt; k += 4) {
      int e0_ = eb[k], e1_ = eb[k + 1], e2_ = eb[k + 2], e3_ = eb[k + 3];
      f16x2 v0 = *(const f16x2*)&MIDs[(size_t)e0_ * 512 + t * 2];
      f16x2 v1 = *(const f16x2*)&MIDs[(size_t)e1_ * 512 + t * 2];
      f16x2 v2 = *(const f16x2*)&MIDs[(size_t)e2_ * 512 + t * 2];
      f16x2 v3 = *(const f16x2*)&MIDs[(size_t)e3_ * 512 + t * 2];
      a0 += (float)v0[0] + (float)v1[0] + (float)v2[0] + (float)v3[0];
      a1 += (float)v0[1] + (float)v1[1] + (float)v2[1] + (float)v3[1];
    }
    for (; k < cnt; ++k) {
      f16x2 v = *(const f16x2*)&MIDs[(size_t)eb[k] * 512 + t * 2];
      a0 += (float)v[0];
      a1 += (float)v[1];
    }
  }
#pragma unroll
  for (int u = 0; u < 2; ++u) {
    int x = t * 2 + u;
    float a = u ? a1 : a0;
    int dst;
    if (x < 128) {
      dst = x * 4;
    } else {
      int xm = x - 128;
      int c = xm >> 7, j = xm & 127;
      dst = j * 4 + 1 + c;
    }
    os[dst] = a;
  }
  __syncthreads();
  *(float2*)&out[(size_t)n * 512 + t * 2] = *(const float2*)&os[t * 2];
}

// ---------------------------------------------------------------------------
extern "C" void kernel_launch(void* const* d_in, const int* in_sizes, int n_in,
                              void* d_out, int out_size, void* d_ws, size_t ws_size,
                              hipStream_t stream) {
  const float* node_feats = (const float*)d_in[1];
  const float* edge_attrs = (const float*)d_in[2];
  const float* edge_feats = (const float*)d_in[3];
  const int*   edge_index = (const int*)d_in[4];
  const float* W_up0   = (const float*)d_in[5];
  const float* W_up1   = (const float*)d_in[6];
  const float* W_down  = (const float*)d_in[7];
  const float* Wm0     = (const float*)d_in[8];
  const float* Wm1     = (const float*)d_in[9];
  const float* Wm2     = (const float*)d_in[10];
  const float* Wm3     = (const float*)d_in[11];
  const float* W_lin0  = (const float*)d_in[12];
  const float* W_lin1  = (const float*)d_in[13];
  const float* W_skip0 = (const float*)d_in[14];
  const float* W_skip1 = (const float*)d_in[15];
  float* out = (float*)d_out;

  char* ws = (char*)d_ws;
  size_t off = 0;
  auto alloc = [&](size_t bytes) {
    void* p = ws + off;
    off = (off + bytes + 255) & ~(size_t)255;
    return p;
  };
  _Float16* UPH   = (_Float16*)alloc((size_t)NN * 512 * 2);
  _Float16* DOWNH = (_Float16*)alloc((size_t)NN * 64 * 2);
  _Float16* W0h   = (_Float16*)alloc(160 * 256 * 2);
  _Float16* W1h   = (_Float16*)alloc(256 * 256 * 2);
  _Float16* W2h   = (_Float16*)alloc(256 * 256 * 2);
  _Float16* W3h   = (_Float16*)alloc(256 * 512 * 2);
  _Float16* WL0h  = (_Float16*)alloc(256 * 128 * 2);
  _Float16* WL1h  = (_Float16*)alloc(256 * 128 * 2);
  int*      CNT   = (int*)alloc((size_t)NN * 4);
  int*      OFF   = (int*)alloc((size_t)(NN + 1) * 4);
  int*      CUR   = (int*)alloc((size_t)NN * 4);
  int*      EIDX  = (int*)alloc((size_t)NE * 4);
  int*      CNT2  = (int*)alloc((size_t)NN * 4);
  int*      OFF2  = (int*)alloc((size_t)(NN + 1) * 4);
  int*      CUR2  = (int*)alloc((size_t)NN * 4);
  int*      SIDX  = (int*)alloc((size_t)NE * 4);
  _Float16* MIDs  = (_Float16*)alloc((size_t)NE * 512 * 2);

  hipMemsetAsync(CNT, 0, (size_t)NN * 4, stream);
  hipMemsetAsync(CNT2, 0, (size_t)NN * 4, stream);

  // scales folded into fp16 weights: 1/sqrt(136) layer0, 1/16 layers 1..3,
  // 1/256 for W_lin (includes sqrt(2C) and AVG_NEIGH)
  wconv<<<160, 256, 0, stream>>>(Wm0, W0h, 136, 160, 256, 1.0f / sqrtf(136.0f), 64);
  wconv<<<256, 256, 0, stream>>>(Wm1, W1h, 256, 256, 256, 0.0625f, 64);
  wconv<<<256, 256, 0, stream>>>(Wm2, W2h, 256, 256, 256, 0.0625f, 64);
  wconv<<<512, 256, 0, stream>>>(Wm3, W3h, 256, 256, 512, 0.0625f, 32);
  wconv<<<128, 256, 0, stream>>>(W_lin0, WL0h, 256, 256, 128, 1.0f / 256.0f, 32);
  wconv<<<128, 256, 0, stream>>>(W_lin1, WL1h, 256, 256, 128, 1.0f / 256.0f, 32);

  node_pre_s<<<625, 256, 0, stream>>>(node_feats, W_up0, W_skip0, W_down,
                                      UPH, DOWNH, out + (size_t)NN * 512);
  node_pre_v<<<625, 256, 0, stream>>>(node_feats, W_up1, W_skip1,
                                      UPH, out + (size_t)NN * 512);

  // receiver CSR (gather) + sender CSR (edge processing order)
  k_count<<<625, 256, 0, stream>>>(edge_index, CNT, 1);
  k_count<<<625, 256, 0, stream>>>(edge_index, CNT2, 0);
  k_scan<<<1, 1024, 0, stream>>>(CNT, OFF, CUR);
  k_scan<<<1, 1024, 0, stream>>>(CNT2, OFF2, CUR2);
  k_fill<<<625, 256, 0, stream>>>(edge_index, CUR, EIDX, 1);
  k_fill<<<625, 256, 0, stream>>>(edge_index, CUR2, SIDX, 0);

  edge_mlp<<<2500, 256, 0, stream>>>(edge_attrs, edge_feats, edge_index, SIDX,
                                     DOWNH, UPH, W0h, W1h, W2h, W3h, WL0h, WL1h,
                                     MIDs);
  gather_msg<<<NN, 256, 0, stream>>>(MIDs, OFF, EIDX, out);
}

// Round 4
// 473.956 us; speedup vs baseline: 1.3411x; 1.1641x over previous
//
#include <hip/hip_runtime.h>
#include <cmath>

#define NN 10000
#define NE 160000
#define INV_SQRT_C 0.08838834764831845f   // 1/sqrt(128)
#define INV_SQRT3F 0.5773502691896258f

typedef _Float16 f16x8 __attribute__((ext_vector_type(8)));
typedef _Float16 f16x4 __attribute__((ext_vector_type(4)));
typedef _Float16 f16x2 __attribute__((ext_vector_type(2)));
typedef float    f32x4 __attribute__((ext_vector_type(4)));

__device__ __forceinline__ float silu_f(float x) {
  return x / (1.f + __expf(-x));
}

// ---------------------------------------------------------------------------
// Weight conversion fp32 -> fp16, all 6 weights in ONE launch.
// blockIdx.y selects the job; per-job params are compile-time constants.
// B-fragment swizzle + column permutation (storage slot ct*16+m within a
// P-chunk holds logical col m*(P/16)+ct).
// ---------------------------------------------------------------------------
__device__ __forceinline__ void wconv_one(
    const float* __restrict__ src, _Float16* __restrict__ dst,
    int Korig, int Kpad, int N, float scale, int P) {
  int total = Kpad * N;
  for (int t = blockIdx.x * blockDim.x + threadIdx.x; t < total;
       t += gridDim.x * blockDim.x) {
    int n = t % N;
    int k = t / N;
    int kb = k >> 5, kk = k & 31;
    int sub = n & (P - 1);
    int n_l = (n & ~(P - 1)) | ((sub & 15) * (P >> 4) + (sub >> 4));
    float v = (k < Korig) ? src[(size_t)k * N + n_l] * scale : 0.f;
    dst[((size_t)(kb * N + n) << 5) + kk] = (_Float16)v;
  }
}

__global__ __launch_bounds__(256) void wconv6(
    const float* __restrict__ s0, const float* __restrict__ s1,
    const float* __restrict__ s2, const float* __restrict__ s3,
    const float* __restrict__ s4, const float* __restrict__ s5,
    _Float16* __restrict__ d0, _Float16* __restrict__ d1,
    _Float16* __restrict__ d2, _Float16* __restrict__ d3,
    _Float16* __restrict__ d4, _Float16* __restrict__ d5) {
  switch (blockIdx.y) {
    case 0: wconv_one(s0, d0, 136, 160, 256, 0.08574929257125442f, 64); break;
    case 1: wconv_one(s1, d1, 256, 256, 256, 0.0625f, 64); break;
    case 2: wconv_one(s2, d2, 256, 256, 256, 0.0625f, 64); break;
    case 3: wconv_one(s3, d3, 256, 256, 512, 0.0625f, 32); break;
    case 4: wconv_one(s4, d4, 256, 256, 128, 1.0f / 256.0f, 32); break;
    default: wconv_one(s5, d5, 256, 256, 128, 1.0f / 256.0f, 32); break;
  }
}

// ---------------------------------------------------------------------------
// Node pre-pass, single launch: blocks [0,625) do the s-tile (up_s, sc_s,
// down); blocks [625,1250) do the v-tile (up_v, sc_v). Same arithmetic as
// the verified two-kernel version.
// ---------------------------------------------------------------------------
__global__ __launch_bounds__(256) void node_pre_all(
    const float* __restrict__ feats,
    const float* __restrict__ W_up0, const float* __restrict__ W_skip0,
    const float* __restrict__ W_down,
    const float* __restrict__ W_up1, const float* __restrict__ W_skip1,
    _Float16* __restrict__ UPH, _Float16* __restrict__ DOWNH,
    float* __restrict__ out_sc) {
  __shared__ float ls[16 * 384];
  const int t = threadIdx.x;
  if (blockIdx.x < 625) {
    const int n0 = blockIdx.x * 16;
    for (int f = t; f < 16 * 128; f += 256) {
      int r = f >> 7, c = f & 127;
      ls[r * 128 + c] = feats[(size_t)(n0 + r) * 512 + c];
    }
    __syncthreads();
    {
      int j = t & 127, g = t >> 7;  // 8 nodes per group
      float au[8] = {0, 0, 0, 0, 0, 0, 0, 0};
      float ak[8] = {0, 0, 0, 0, 0, 0, 0, 0};
      for (int i = 0; i < 128; ++i) {
        float wu = W_up0[(size_t)i * 128 + j];
        float wk = W_skip0[(size_t)i * 128 + j];
#pragma unroll
        for (int r = 0; r < 8; ++r) {
          float s = ls[(g * 8 + r) * 128 + i];
          au[r] += s * wu;
          ak[r] += s * wk;
        }
      }
#pragma unroll
      for (int r = 0; r < 8; ++r) {
        int n = n0 + g * 8 + r;
        UPH[(size_t)n * 512 + j] = (_Float16)(au[r] * INV_SQRT_C);
        out_sc[(size_t)n * 512 + j] = ak[r] * INV_SQRT_C;
      }
    }
    {
      int j = t & 63, g = t >> 6;  // 4 nodes per group
      float ad[4] = {0, 0, 0, 0};
      for (int i = 0; i < 128; ++i) {
        float wd = W_down[(size_t)i * 64 + j];
#pragma unroll
        for (int r = 0; r < 4; ++r) ad[r] += ls[(g * 4 + r) * 128 + i] * wd;
      }
#pragma unroll
      for (int r = 0; r < 4; ++r)
        DOWNH[(size_t)(n0 + g * 4 + r) * 64 + j] = (_Float16)(ad[r] * INV_SQRT_C);
    }
  } else {
    const int n0 = (blockIdx.x - 625) * 16;
    for (int f = t; f < 16 * 384; f += 256) {
      int r = f / 384, c = f % 384;
      ls[r * 384 + c] = feats[(size_t)(n0 + r) * 512 + 128 + c];
    }
    __syncthreads();
    int j = t & 127, g = t >> 7;
    float au[8][3], ak[8][3];
#pragma unroll
    for (int r = 0; r < 8; ++r)
#pragma unroll
      for (int c = 0; c < 3; ++c) { au[r][c] = 0.f; ak[r][c] = 0.f; }
    for (int i = 0; i < 128; ++i) {
      float wu = W_up1[(size_t)i * 128 + j];
      float wk = W_skip1[(size_t)i * 128 + j];
#pragma unroll
      for (int r = 0; r < 8; ++r) {
#pragma unroll
        for (int c = 0; c < 3; ++c) {
          float v = ls[(g * 8 + r) * 384 + i * 3 + c];
          au[r][c] += v * wu;
          ak[r][c] += v * wk;
        }
      }
    }
#pragma unroll
    for (int r = 0; r < 8; ++r) {
      int n = n0 + g * 8 + r;
#pragma unroll
      for (int c = 0; c < 3; ++c) {
        UPH[(size_t)n * 512 + 128 + j * 3 + c] = (_Float16)(au[r][c] * INV_SQRT_C);
        out_sc[(size_t)n * 512 + 128 + j * 3 + c] = ak[r][c] * INV_SQRT_C;
      }
    }
  }
}

// ---------------------------------------------------------------------------
// CSR build, fused: one count pass (both endpoints), one scan launch
// (grid=2, one block per scan), one fill pass. EIDX stores the SENDER-SORTED
// POSITION of each receiver-CSR edge, so gather reads MIDs rows written
// contiguously by edge_mlp.
// ---------------------------------------------------------------------------
__global__ void k_count2(const int* __restrict__ edge_index,
                         int* __restrict__ CNT, int* __restrict__ CNT2) {
  int e = blockIdx.x * blockDim.x + threadIdx.x;
  if (e < NE) {
    int2 sr = *(const int2*)&edge_index[(size_t)e * 2];
    atomicAdd(&CNT[sr.y], 1);    // receiver
    atomicAdd(&CNT2[sr.x], 1);   // sender
  }
}

__device__ __forceinline__ void scan_one(const int* __restrict__ CNT,
                                         int* __restrict__ OFF,
                                         int* __restrict__ CUR, int* ts) {
  const int t = threadIdx.x;
  const int base = t * 10;
  int loc[10];
  int s = 0;
#pragma unroll
  for (int i = 0; i < 10; ++i) {
    int idx = base + i;
    int v = (idx < NN) ? CNT[idx] : 0;
    loc[i] = s;
    s += v;
  }
  ts[t] = s;
  __syncthreads();
  for (int off = 1; off < 1024; off <<= 1) {
    int v = (t >= off) ? ts[t - off] : 0;
    __syncthreads();
    ts[t] += v;
    __syncthreads();
  }
  int tp = (t > 0) ? ts[t - 1] : 0;
#pragma unroll
  for (int i = 0; i < 10; ++i) {
    int idx = base + i;
    if (idx < NN) {
      OFF[idx] = tp + loc[i];
      CUR[idx] = tp + loc[i];
    }
  }
  if (t == 1023) OFF[NN] = ts[1023];
}

__global__ __launch_bounds__(1024) void k_scan2(
    const int* __restrict__ CNT, int* __restrict__ OFF, int* __restrict__ CUR,
    const int* __restrict__ CNT2, int* __restrict__ OFF2, int* __restrict__ CUR2) {
  __shared__ int ts[1024];
  if (blockIdx.x == 0) scan_one(CNT, OFF, CUR, ts);
  else                 scan_one(CNT2, OFF2, CUR2, ts);
}

__global__ void k_fill2(const int* __restrict__ edge_index,
                        int* __restrict__ CUR, int* __restrict__ EIDX,
                        int* __restrict__ CUR2, int* __restrict__ SIDX) {
  int e = blockIdx.x * blockDim.x + threadIdx.x;
  if (e < NE) {
    int2 sr = *(const int2*)&edge_index[(size_t)e * 2];
    int ps = atomicAdd(&CUR2[sr.x], 1);  // sender-sorted position
    SIDX[ps] = e;
    int pr = atomicAdd(&CUR[sr.y], 1);   // receiver-CSR slot
    EIDX[pr] = ps;                       // gather reads MIDs[ps]
  }
}

// ---------------------------------------------------------------------------
// Fused edge kernel — round-0 verified structure (HA/HB ping-pong, SW/SP
// separate, original barrier schedule; 64 KB LDS, 2 blocks/CU, 128 VGPR).
// Round-3 additions (setprio, XCD swizzle) REVERTED: measured −11%
// (lockstep waves -> setprio churn; not HBM-bound -> swizzle useless).
// Only change vs round-0: MIDs rows are indexed by SENDER-SORTED position
// (e0 + row) => contiguous per block (no scattered elw-addressed writes, no
// partial-line RMW). gather compensates via EIDX holding sender positions.
// ---------------------------------------------------------------------------
__device__ __forceinline__ void mlp_layer_256(
    const _Float16* In, _Float16* Out, const _Float16* __restrict__ Wz,
    int m, int g, int wv) {
  f32x4 acc[4][4];
  f32x4 zero4 = {0.f, 0.f, 0.f, 0.f};
#pragma unroll
  for (int rt = 0; rt < 4; ++rt)
#pragma unroll
    for (int ct = 0; ct < 4; ++ct) acc[rt][ct] = zero4;

#pragma unroll
  for (int kb = 0; kb < 8; ++kb) {
    f16x8 a[4], b[4];
#pragma unroll
    for (int rt = 0; rt < 4; ++rt) {
      int row = rt * 16 + m;
      a[rt] = *(const f16x8*)&In[row * 256 + (((kb * 2 + (g >> 1)) ^ m) << 4) + (g & 1) * 8];
    }
#pragma unroll
    for (int ct = 0; ct < 4; ++ct)
      b[ct] = *(const f16x8*)&Wz[((size_t)(kb * 256 + wv * 64 + ct * 16 + m) << 5) + g * 8];
#pragma unroll
    for (int rt = 0; rt < 4; ++rt)
#pragma unroll
      for (int ct = 0; ct < 4; ++ct)
        acc[rt][ct] = __builtin_amdgcn_mfma_f32_16x16x32_f16(a[rt], b[ct], acc[rt][ct], 0, 0, 0);
  }
#pragma unroll
  for (int rt = 0; rt < 4; ++rt)
#pragma unroll
    for (int q = 0; q < 4; ++q) {
      int row = rt * 16 + g * 4 + q;
      f16x4 pk;
#pragma unroll
      for (int ct = 0; ct < 4; ++ct) pk[ct] = (_Float16)silu_f(acc[rt][ct][q]);
      int blk = (wv * 4 + (m >> 2)) ^ (row & 15);
      *(f16x4*)&Out[row * 256 + (blk << 4) + (m & 3) * 4] = pk;
    }
}

__global__ __launch_bounds__(256, 2) void edge_mlp(
    const float* __restrict__ edge_attrs,
    const float* __restrict__ edge_feats,
    const int* __restrict__ edge_index,
    const int* __restrict__ SIDX,
    const _Float16* __restrict__ DOWNH,
    const _Float16* __restrict__ UPH,
    const _Float16* __restrict__ W0h, const _Float16* __restrict__ W1h,
    const _Float16* __restrict__ W2h, const _Float16* __restrict__ W3h,
    const _Float16* __restrict__ WL0h, const _Float16* __restrict__ WL1h,
    _Float16* __restrict__ MIDs) {
  __shared__ _Float16 HA[64 * 256];
  __shared__ _Float16 HB[64 * 256];

  const int tid = threadIdx.x;
  const int lane = tid & 63;
  const int wv = tid >> 6;
  const int m = lane & 15;
  const int g = lane >> 4;
  const int e0 = blockIdx.x * 64;
  const int nw = wv * 64;

  int el_r[4], snd_r[4], rcv_r[4];
#pragma unroll
  for (int rt = 0; rt < 4; ++rt) {
    el_r[rt] = SIDX[e0 + rt * 16 + m];
    int2 sr = *(const int2*)&edge_index[(size_t)el_r[rt] * 2];
    snd_r[rt] = sr.x;
    rcv_r[rt] = sr.y;
  }

  f32x4 zero4 = {0.f, 0.f, 0.f, 0.f};
  f16x8 zf = {0, 0, 0, 0, 0, 0, 0, 0};

  // ---------------- layer 0: aug(136, padded 160) -> h1 (HA)
  {
    f32x4 acc[4][4];
#pragma unroll
    for (int rt = 0; rt < 4; ++rt)
#pragma unroll
      for (int ct = 0; ct < 4; ++ct) acc[rt][ct] = zero4;

#pragma unroll
    for (int kb = 0; kb < 5; ++kb) {
      const int k0 = kb * 32 + g * 8;
      f16x8 a[4], b[4];
#pragma unroll
      for (int rt = 0; rt < 4; ++rt) {
        if (k0 == 0) {
          const float* ef = &edge_feats[(size_t)el_r[rt] * 8];
          float4 f0 = *(const float4*)ef;
          float4 f1 = *(const float4*)(ef + 4);
          f16x8 av;
          av[0] = (_Float16)f0.x; av[1] = (_Float16)f0.y;
          av[2] = (_Float16)f0.z; av[3] = (_Float16)f0.w;
          av[4] = (_Float16)f1.x; av[5] = (_Float16)f1.y;
          av[6] = (_Float16)f1.z; av[7] = (_Float16)f1.w;
          a[rt] = av;
        } else if (k0 < 72) {
          a[rt] = *(const f16x8*)&DOWNH[(size_t)snd_r[rt] * 64 + (k0 - 8)];
        } else if (k0 < 136) {
          a[rt] = *(const f16x8*)&DOWNH[(size_t)rcv_r[rt] * 64 + (k0 - 72)];
        } else {
          a[rt] = zf;
        }
      }
#pragma unroll
      for (int ct = 0; ct < 4; ++ct)
        b[ct] = *(const f16x8*)&W0h[((size_t)(kb * 256 + nw + ct * 16 + m) << 5) + g * 8];
#pragma unroll
      for (int rt = 0; rt < 4; ++rt)
#pragma unroll
        for (int ct = 0; ct < 4; ++ct)
          acc[rt][ct] = __builtin_amdgcn_mfma_f32_16x16x32_f16(a[rt], b[ct], acc[rt][ct], 0, 0, 0);
    }
#pragma unroll
    for (int rt = 0; rt < 4; ++rt)
#pragma unroll
      for (int q = 0; q < 4; ++q) {
        int row = rt * 16 + g * 4 + q;
        f16x4 pk;
#pragma unroll
        for (int ct = 0; ct < 4; ++ct) pk[ct] = (_Float16)silu_f(acc[rt][ct][q]);
        int blk = (wv * 4 + (m >> 2)) ^ (row & 15);
        *(f16x4*)&HA[row * 256 + (blk << 4) + (m & 3) * 4] = pk;
      }
  }
  __syncthreads();

  mlp_layer_256(HA, HB, W1h, m, g, wv);   // layer 1: h1 -> h2
  __syncthreads();
  mlp_layer_256(HB, HA, W2h, m, g, wv);   // layer 2: h2 -> h3 (HA stays live)
  __syncthreads();

  // ================= epilogue =================
  _Float16* SW = HB;             // 64 x 128 fp16, tpw quarter
  _Float16* SP = HB + 64 * 128;  // 64 x 128 fp16, TP'd A-matrix

  const int e_loc = lane;
  const int ers = (e_loc ^ (e_loc >> 3)) & 7;
  const int elc = SIDX[e0 + e_loc];
  const int snd_e = edge_index[(size_t)elc * 2];
  const _Float16* uprow = &UPH[(size_t)snd_e * 512];

  // quarter GEMM into caller-provided acc buffer
  auto qgemm = [&](int qbase, f32x4 (&accq)[4][2]) {
#pragma unroll
    for (int rt = 0; rt < 4; ++rt)
#pragma unroll
      for (int ct = 0; ct < 2; ++ct) accq[rt][ct] = zero4;
#pragma unroll
    for (int kb = 0; kb < 8; ++kb) {
      f16x8 a[4], b[2];
#pragma unroll
      for (int rt = 0; rt < 4; ++rt) {
        int row = rt * 16 + m;
        a[rt] = *(const f16x8*)&HA[row * 256 + (((kb * 2 + (g >> 1)) ^ m) << 4) + (g & 1) * 8];
      }
#pragma unroll
      for (int ct = 0; ct < 2; ++ct)
        b[ct] = *(const f16x8*)&W3h[((size_t)(kb * 512 + qbase + wv * 32 + ct * 16 + m) << 5) + g * 8];
#pragma unroll
      for (int rt = 0; rt < 4; ++rt)
#pragma unroll
        for (int ct = 0; ct < 2; ++ct)
          accq[rt][ct] = __builtin_amdgcn_mfma_f32_16x16x32_f16(a[rt], b[ct], accq[rt][ct], 0, 0, 0);
    }
  };

  auto sw_write = [&](const f32x4 (&accq)[4][2]) {
#pragma unroll
    for (int rt = 0; rt < 4; ++rt)
#pragma unroll
      for (int r4 = 0; r4 < 4; ++r4) {
        int row = rt * 16 + g * 4 + r4;
        int rs = (row ^ (row >> 3)) & 7;
        f16x2 pk;
        pk[0] = (_Float16)accq[rt][0][r4];
        pk[1] = (_Float16)accq[rt][1][r4];
        int blk = ((wv * 2 + (m >> 3)) ^ rs) & 7;
        *(f16x2*)&SW[row * 128 + (blk << 4) + (m & 7) * 2] = pk;
      }
  };

  auto fold = [&](const _Float16* __restrict__ WLh, int qpart, f32x4 (&P)[4][2]) {
#pragma unroll
    for (int rt = 0; rt < 4; ++rt)
#pragma unroll
      for (int ct = 0; ct < 2; ++ct) P[rt][ct] = zero4;
#pragma unroll
    for (int kb = 0; kb < 4; ++kb) {
      f16x8 a[4], b[2];
#pragma unroll
      for (int rt = 0; rt < 4; ++rt) {
        int row = rt * 16 + m;
        int rs = (row ^ (row >> 3)) & 7;
        a[rt] = *(const f16x8*)&SP[row * 128 + ((((kb * 2 + (g >> 1)) ^ rs) & 7) << 4) + (g & 1) * 8];
      }
#pragma unroll
      for (int ct = 0; ct < 2; ++ct)
        b[ct] = *(const f16x8*)&WLh[((size_t)((qpart * 4 + kb) * 128 + wv * 32 + ct * 16 + m) << 5) + g * 8];
#pragma unroll
      for (int rt = 0; rt < 4; ++rt)
#pragma unroll
        for (int ct = 0; ct < 2; ++ct)
          P[rt][ct] = __builtin_amdgcn_mfma_f32_16x16x32_f16(a[rt], b[ct], P[rt][ct], 0, 0, 0);
    }
  };

  auto tp_xs = [&]() {
#pragma unroll
    for (int cch = 0; cch < 4; ++cch) {
      int ib = nw / 2 + cch * 8;
      int blk = ((ib >> 4) ^ ers) & 7;
      int off = e_loc * 128 + (blk << 4) + (ib & 15);
      f16x8 swv = *(const f16x8*)&SW[off];
      f16x8 upv = *(const f16x8*)&uprow[ib];
      f16x8 pr = swv * upv;
      *(f16x8*)&SP[off] = pr;
    }
  };

  _Float16 xvb[96];
  auto load_xv = [&]() {
#pragma unroll
    for (int u = 0; u < 12; ++u) {
      f16x8 t = *(const f16x8*)&uprow[128 + wv * 96 + u * 8];
#pragma unroll
      for (int z = 0; z < 8; ++z) xvb[u * 8 + z] = t[z];
    }
  };

  auto tp_w4 = [&]() {
    float4 ea = *(const float4*)&edge_attrs[(size_t)elc * 4];
#pragma unroll
    for (int cch = 0; cch < 4; ++cch) {
      int ib = nw / 2 + cch * 8;
      int blk = ((ib >> 4) ^ ers) & 7;
      int off = e_loc * 128 + (blk << 4) + (ib & 15);
      f16x8 swv = *(const f16x8*)&SW[off];
      f16x8 outv;
#pragma unroll
      for (int z = 0; z < 8; ++z) {
        int k = cch * 8 + z;
        float d = (float)xvb[k * 3] * ea.y + (float)xvb[k * 3 + 1] * ea.z +
                  (float)xvb[k * 3 + 2] * ea.w;
        outv[z] = (_Float16)((float)swv[z] * d);
      }
      *(f16x8*)&SP[off] = outv;
    }
  };

  auto tp_w3 = [&](int c) {
#pragma unroll
    for (int cch = 0; cch < 4; ++cch) {
      int ib = nw / 2 + cch * 8;
      int blk = ((ib >> 4) ^ ers) & 7;
      int off = e_loc * 128 + (blk << 4) + (ib & 15);
      f16x8 swv = *(const f16x8*)&SW[off];
      f16x8 outv;
#pragma unroll
      for (int z = 0; z < 8; ++z) {
        int k = cch * 8 + z;
        outv[z] = swv[z] * xvb[k * 3 + c];
      }
      *(f16x8*)&SP[off] = outv;
    }
  };

  f32x4 accqA[4][2], accqB[4][2];
  f32x4 P1[4][2], P4[4][2], P2[4][2], P3[4][2];

  // q1 (w1): A1 = w1 (x) xs ; P1 = A1 @ WL0a. Queue q4 gemm before barrier.
  qgemm(0, accqA);
  sw_write(accqA);
  tp_xs();
  qgemm(384, accqB);          // w4, independent — fills the barrier wait
  __syncthreads();            // B1: SP(A1) complete
  fold(WL0h, 0, P1);
  sw_write(accqB);            // SW <- w4 (SW(w1) readers all pre-B1)
  load_xv();
  __syncthreads();            // B2: all folds done reading SP(A1)
  tp_w4();
  qgemm(128, accqA);          // w2 queued
  __syncthreads();            // B3: SP(A4) complete
  fold(WL0h, 1, P4);
  sw_write(accqA);            // SW <- w2 (tp_w4 reads all pre-B3)

  // scalar part: MIDs[:, j] = y0*P1 + P4/sqrt(3). Row = sender-sorted pos.
#pragma unroll
  for (int rt = 0; rt < 4; ++rt)
#pragma unroll
    for (int r4 = 0; r4 < 4; ++r4) {
      int row = rt * 16 + g * 4 + r4;
      int elw = SIDX[e0 + row];
      float4 ea = *(const float4*)&edge_attrs[(size_t)elw * 4];
      f16x2 pk;
      pk[0] = (_Float16)(ea.x * P1[rt][0][r4] + INV_SQRT3F * P4[rt][0][r4]);
      pk[1] = (_Float16)(ea.x * P1[rt][1][r4] + INV_SQRT3F * P4[rt][1][r4]);
      *(f16x2*)&MIDs[(size_t)(e0 + row) * 512 + wv * 32 + m * 2] = pk;
    }
  __syncthreads();            // B4: folds done reading SP(A4)
  tp_xs();                    // SP <- A2 (reads SW(w2), own wave, pre-B4)
  qgemm(256, accqB);          // w3 queued
  __syncthreads();            // B5: SP(A2) complete
  fold(WL1h, 0, P2);
  sw_write(accqB);            // SW <- w3 (tp_xs reads all pre-B5)
  __syncthreads();            // B6: folds done reading SP(A2)

#pragma unroll
  for (int c = 0; c < 3; ++c) {
    tp_w3(c);                 // SP <- A3c (reads SW(w3), own wave)
    __syncthreads();          // SP complete
    fold(WL1h, 1, P3);
    // plane c: MIDs[:, 128 + c*128 + j] = yv[c]*P2 + y0*P3
#pragma unroll
    for (int rt = 0; rt < 4; ++rt)
#pragma unroll
      for (int r4 = 0; r4 < 4; ++r4) {
        int row = rt * 16 + g * 4 + r4;
        int elw = SIDX[e0 + row];
        float4 ea = *(const float4*)&edge_attrs[(size_t)elw * 4];
        float yvc = (c == 0) ? ea.y : (c == 1) ? ea.z : ea.w;
        f16x2 pk;
        pk[0] = (_Float16)(yvc * P2[rt][0][r4] + ea.x * P3[rt][0][r4]);
        pk[1] = (_Float16)(yvc * P2[rt][1][r4] + ea.x * P3[rt][1][r4]);
        *(f16x2*)&MIDs[(size_t)(e0 + row) * 512 + 128 + c * 128 + wv * 32 + m * 2] = pk;
      }
    if (c < 2) __syncthreads();  // folds done reading SP before next tp_w3
  }
}

// ---------------------------------------------------------------------------
// Gather: one block per node; LDS-staged edge ids + 4-way unroll; output row
// staged in LDS and stored coalesced (float2/lane). EIDX now holds sender-
// sorted positions => MIDs rows are whatever edge_mlp wrote at those rows.
// ---------------------------------------------------------------------------
__global__ __launch_bounds__(256) void gather_msg(
    const _Float16* __restrict__ MIDs, const int* __restrict__ OFF,
    const int* __restrict__ EIDX, float* __restrict__ out) {
  __shared__ int eb[256];
  __shared__ float os[512];
  const int n = blockIdx.x;
  const int t = threadIdx.x;
  const int beg = OFF[n], end = OFF[n + 1];
  float a0 = 0.f, a1 = 0.f;
  for (int base = beg; base < end; base += 256) {
    int cnt = min(256, end - base);
    __syncthreads();
    if (t < cnt) eb[t] = EIDX[base + t];
    __syncthreads();
    int k = 0;
    for (; k + 4 <= cnt; k += 4) {
      int e0_ = eb[k], e1_ = eb[k + 1], e2_ = eb[k + 2], e3_ = eb[k + 3];
      f16x2 v0 = *(const f16x2*)&MIDs[(size_t)e0_ * 512 + t * 2];
      f16x2 v1 = *(const f16x2*)&MIDs[(size_t)e1_ * 512 + t * 2];
      f16x2 v2 = *(const f16x2*)&MIDs[(size_t)e2_ * 512 + t * 2];
      f16x2 v3 = *(const f16x2*)&MIDs[(size_t)e3_ * 512 + t * 2];
      a0 += (float)v0[0] + (float)v1[0] + (float)v2[0] + (float)v3[0];
      a1 += (float)v0[1] + (float)v1[1] + (float)v2[1] + (float)v3[1];
    }
    for (; k < cnt; ++k) {
      f16x2 v = *(const f16x2*)&MIDs[(size_t)eb[k] * 512 + t * 2];
      a0 += (float)v[0];
      a1 += (float)v[1];
    }
  }
#pragma unroll
  for (int u = 0; u < 2; ++u) {
    int x = t * 2 + u;
    float a = u ? a1 : a0;
    int dst;
    if (x < 128) {
      dst = x * 4;
    } else {
      int xm = x - 128;
      int c = xm >> 7, j = xm & 127;
      dst = j * 4 + 1 + c;
    }
    os[dst] = a;
  }
  __syncthreads();
  *(float2*)&out[(size_t)n * 512 + t * 2] = *(const float2*)&os[t * 2];
}

// ---------------------------------------------------------------------------
extern "C" void kernel_launch(void* const* d_in, const int* in_sizes, int n_in,
                              void* d_out, int out_size, void* d_ws, size_t ws_size,
                              hipStream_t stream) {
  const float* node_feats = (const float*)d_in[1];
  const float* edge_attrs = (const float*)d_in[2];
  const float* edge_feats = (const float*)d_in[3];
  const int*   edge_index = (const int*)d_in[4];
  const float* W_up0   = (const float*)d_in[5];
  const float* W_up1   = (const float*)d_in[6];
  const float* W_down  = (const float*)d_in[7];
  const float* Wm0     = (const float*)d_in[8];
  const float* Wm1     = (const float*)d_in[9];
  const float* Wm2     = (const float*)d_in[10];
  const float* Wm3     = (const float*)d_in[11];
  const float* W_lin0  = (const float*)d_in[12];
  const float* W_lin1  = (const float*)d_in[13];
  const float* W_skip0 = (const float*)d_in[14];
  const float* W_skip1 = (const float*)d_in[15];
  float* out = (float*)d_out;

  char* ws = (char*)d_ws;
  size_t off = 0;
  auto alloc = [&](size_t bytes) {
    void* p = ws + off;
    off = (off + bytes + 255) & ~(size_t)255;
    return p;
  };
  _Float16* UPH   = (_Float16*)alloc((size_t)NN * 512 * 2);
  _Float16* DOWNH = (_Float16*)alloc((size_t)NN * 64 * 2);
  _Float16* W0h   = (_Float16*)alloc(160 * 256 * 2);
  _Float16* W1h   = (_Float16*)alloc(256 * 256 * 2);
  _Float16* W2h   = (_Float16*)alloc(256 * 256 * 2);
  _Float16* W3h   = (_Float16*)alloc(256 * 512 * 2);
  _Float16* WL0h  = (_Float16*)alloc(256 * 128 * 2);
  _Float16* WL1h  = (_Float16*)alloc(256 * 128 * 2);
  int*      CNTS  = (int*)alloc((size_t)2 * NN * 4);  // CNT | CNT2, one memset
  int*      CNT   = CNTS;
  int*      CNT2  = CNTS + NN;
  int*      OFF   = (int*)alloc((size_t)(NN + 1) * 4);
  int*      CUR   = (int*)alloc((size_t)NN * 4);
  int*      EIDX  = (int*)alloc((size_t)NE * 4);
  int*      OFF2  = (int*)alloc((size_t)(NN + 1) * 4);
  int*      CUR2  = (int*)alloc((size_t)NN * 4);
  int*      SIDX  = (int*)alloc((size_t)NE * 4);
  _Float16* MIDs  = (_Float16*)alloc((size_t)NE * 512 * 2);

  hipMemsetAsync(CNTS, 0, (size_t)2 * NN * 4, stream);

  // scales folded into fp16 weights: 1/sqrt(136) layer0, 1/16 layers 1..3,
  // 1/256 for W_lin (includes sqrt(2C) and AVG_NEIGH)
  wconv6<<<dim3(128, 6), 256, 0, stream>>>(Wm0, Wm1, Wm2, Wm3, W_lin0, W_lin1,
                                           W0h, W1h, W2h, W3h, WL0h, WL1h);

  node_pre_all<<<1250, 256, 0, stream>>>(node_feats, W_up0, W_skip0, W_down,
                                         W_up1, W_skip1,
                                         UPH, DOWNH, out + (size_t)NN * 512);

  // receiver CSR (gather) + sender CSR (edge processing order), fused
  k_count2<<<625, 256, 0, stream>>>(edge_index, CNT, CNT2);
  k_scan2<<<2, 1024, 0, stream>>>(CNT, OFF, CUR, CNT2, OFF2, CUR2);
  k_fill2<<<625, 256, 0, stream>>>(edge_index, CUR, EIDX, CUR2, SIDX);

  edge_mlp<<<2500, 256, 0, stream>>>(edge_attrs, edge_feats, edge_index, SIDX,
                                     DOWNH, UPH, W0h, W1h, W2h, W3h, WL0h, WL1h,
                                     MIDs);
  gather_msg<<<NN, 256, 0, stream>>>(MIDs, OFF, EIDX, out);
}